// Round 1
// baseline (3327.536 us; speedup 1.0000x reference)
//
#include <hip/hip_runtime.h>
#include <hip/hip_bf16.h>
#include <cstdint>
#include <cstddef>

#define BB 8
#define NHH 8
#define NQ 3137      // 56*56+1
#define NKV 785      // 28*28+1
#define HDIM 64
#define DIM3 1536
#define MROWS (BB*NQ)   // 25096

using bf16 = __hip_bfloat16;

// ---------------------------------------------------------------------------
// GEMM: C = A(M,512) @ W(N,512)^T + bias.  EPI 0: scatter-store bf16 into
// qkv_raw[(which,b,y,tok,c)].  EPI 1: f32 store to out[m*512 + n].
// BM=BN=64, BK=16, 256 threads, 4x4 register tile.
// ---------------------------------------------------------------------------
template<int EPI>
__global__ __launch_bounds__(256) void gemm_bt_kernel(
    const float* __restrict__ A, const float* __restrict__ W,
    const float* __restrict__ bias, void* __restrict__ outp, int M) {
  __shared__ float As[16][68];
  __shared__ float Bs[16][68];
  const int tid = threadIdx.x;
  const int tx = tid & 15, ty = tid >> 4;
  const int m0 = blockIdx.y * 64, n0 = blockIdx.x * 64;
  const int lm = tid >> 2;          // 0..63
  const int lk = (tid & 3) * 4;     // 0,4,8,12
  const float* Arow = A + (size_t)(m0 + lm) * 512;
  const float* Wrow = W + (size_t)(n0 + lm) * 512;
  const bool aok = (m0 + lm) < M;
  float acc[4][4] = {};
  for (int k0 = 0; k0 < 512; k0 += 16) {
    float4 av = aok ? *(const float4*)(Arow + k0 + lk) : make_float4(0.f,0.f,0.f,0.f);
    float4 bv = *(const float4*)(Wrow + k0 + lk);
    __syncthreads();
    As[lk+0][lm] = av.x; As[lk+1][lm] = av.y; As[lk+2][lm] = av.z; As[lk+3][lm] = av.w;
    Bs[lk+0][lm] = bv.x; Bs[lk+1][lm] = bv.y; Bs[lk+2][lm] = bv.z; Bs[lk+3][lm] = bv.w;
    __syncthreads();
    #pragma unroll
    for (int kk = 0; kk < 16; ++kk) {
      float4 a = *(const float4*)(&As[kk][ty*4]);
      float4 b = *(const float4*)(&Bs[kk][tx*4]);
      acc[0][0] += a.x*b.x; acc[0][1] += a.x*b.y; acc[0][2] += a.x*b.z; acc[0][3] += a.x*b.w;
      acc[1][0] += a.y*b.x; acc[1][1] += a.y*b.y; acc[1][2] += a.y*b.z; acc[1][3] += a.y*b.w;
      acc[2][0] += a.z*b.x; acc[2][1] += a.z*b.y; acc[2][2] += a.z*b.z; acc[2][3] += a.z*b.w;
      acc[3][0] += a.w*b.x; acc[3][1] += a.w*b.y; acc[3][2] += a.w*b.z; acc[3][3] += a.w*b.w;
    }
  }
  #pragma unroll
  for (int i = 0; i < 4; ++i) {
    const int m = m0 + ty*4 + i;
    if (m >= M) continue;
    #pragma unroll
    for (int j = 0; j < 4; ++j) {
      const int jn = n0 + tx*4 + j;
      const float v = acc[i][j] + bias[jn];
      if (EPI == 0) {
        const int which = jn >> 9, y = (jn >> 6) & 7, c = jn & 63;
        const int b_ = m / NQ, tok = m - b_ * NQ;
        const size_t idx = ((((size_t)which*BB + b_)*NHH + y)*NQ + tok)*HDIM + c;
        ((bf16*)outp)[idx] = __float2bfloat16(v);
      } else {
        ((float*)outp)[(size_t)m * 512 + jn] = v;
      }
    }
  }
}

// ---------------------------------------------------------------------------
// Depthwise 3x3 pool (zero-pad 1) + LayerNorm over HD=64 (one wave per row).
// in: bf16 (b,y,tok,c) with tok in [0,3137); out: f32 (b,y,n,c), n in [0,R).
// ---------------------------------------------------------------------------
__global__ __launch_bounds__(256) void pool_ln_kernel(
    const bf16* __restrict__ in, float* __restrict__ outp,
    const float* __restrict__ cw, const float* __restrict__ lnw,
    const float* __restrict__ lnb, int stride, int OW, int R) {
  const int tid = threadIdx.x;
  const int c = tid & 63;
  const int rid = blockIdx.x * 4 + (tid >> 6);
  const int by = rid / R;
  const int n = rid - by * R;
  const bf16* ibase = in + (size_t)by * NQ * HDIM;
  float val;
  if (n == 0) {
    val = __bfloat162float(ibase[c]);
  } else {
    const int p = n - 1;
    const int ho = p / OW, wo = p - ho * OW;
    float s = 0.f;
    #pragma unroll
    for (int dh = 0; dh < 3; ++dh) {
      const int hh = ho * stride + dh - 1;
      if (hh < 0 || hh >= 56) continue;
      #pragma unroll
      for (int dw = 0; dw < 3; ++dw) {
        const int ww = wo * stride + dw - 1;
        if (ww < 0 || ww >= 56) continue;
        s += cw[c*9 + dh*3 + dw] *
             __bfloat162float(ibase[(size_t)(1 + hh*56 + ww)*HDIM + c]);
      }
    }
    val = s;
  }
  float sum = val, sq = val * val;
  #pragma unroll
  for (int off = 32; off > 0; off >>= 1) {
    sum += __shfl_xor(sum, off);
    sq  += __shfl_xor(sq,  off);
  }
  const float mean = sum * (1.f/64.f);
  const float var  = sq  * (1.f/64.f) - mean*mean;
  const float rs = rsqrtf(var + 1e-6f);
  outp[(size_t)rid * HDIM + c] = (val - mean) * rs * lnw[c] + lnb[c];
}

// ---------------------------------------------------------------------------
// rel_h[r,kh] = sum_c q_p[by, 1+p, c] * rel_pos_h[h-2kh+54, c]   (r=(by,p))
// rel_w[r,kw] = sum_c q_p[by, 1+p, c] * rel_pos_w[w-2kw+54, c]
// One wave per q body row; lanes 0..27 -> rel_h, lanes 32..59 -> rel_w.
// ---------------------------------------------------------------------------
__global__ __launch_bounds__(256) void relbias_kernel(
    const float* __restrict__ qp, const float* __restrict__ rph,
    const float* __restrict__ rpw, float* __restrict__ relh,
    float* __restrict__ relw) {
  __shared__ float qs[4][64];
  const int tid = threadIdx.x;
  const int l = tid & 63;
  const int wv = tid >> 6;
  const int r = blockIdx.x * 4 + wv;
  const int by = r / 3136;
  const int p = r - by * 3136;
  const int h = p / 56, w = p - h * 56;
  qs[wv][l] = qp[((size_t)by * NQ + 1 + p) * HDIM + l];
  __syncthreads();
  const float* rp;
  if (l < 28)                 rp = rph + (size_t)(h - 2*l + 54) * 64;
  else if (l >= 32 && l < 60) rp = rpw + (size_t)(w - 2*(l-32) + 54) * 64;
  else                        rp = rph;
  float dot = 0.f;
  #pragma unroll
  for (int i = 0; i < 16; ++i) {
    float4 rv = ((const float4*)rp)[i];
    dot += qs[wv][4*i+0]*rv.x + qs[wv][4*i+1]*rv.y
         + qs[wv][4*i+2]*rv.z + qs[wv][4*i+3]*rv.w;
  }
  if (l < 28)                 relh[(size_t)r*28 + l]        = dot;
  else if (l >= 32 && l < 60) relw[(size_t)r*28 + (l-32)]   = dot;
}

// ---------------------------------------------------------------------------
// Attention: one thread per q row; online softmax over 785 cols in chunks of
// 4; bias = rel_h[kh] + rel_w[kw] on body block; residual add of pooled q.
// Writes f32 out (B, N, NH*HD) ready for proj GEMM.
// ---------------------------------------------------------------------------
__global__ __launch_bounds__(256) void attn_kernel(
    const float* __restrict__ qp, const float* __restrict__ kp,
    const float* __restrict__ vp, const float* __restrict__ relh,
    const float* __restrict__ relw, float* __restrict__ outp) {
  const int n = blockIdx.x * 256 + threadIdx.x;
  if (n >= NQ) return;
  const int by = blockIdx.y;          // b*8 + y
  const float* qrow = qp + ((size_t)by * NQ + n) * HDIM;
  float q[64];
  #pragma unroll
  for (int i = 0; i < 16; ++i) {
    float4 t = ((const float4*)qrow)[i];
    q[4*i+0] = t.x * 0.125f; q[4*i+1] = t.y * 0.125f;
    q[4*i+2] = t.z * 0.125f; q[4*i+3] = t.w * 0.125f;
  }
  const float* kb = kp + (size_t)by * NKV * HDIM;
  const float* vb = vp + (size_t)by * NKV * HDIM;
  float o[64];
  #pragma unroll
  for (int i = 0; i < 64; ++i) o[i] = 0.f;
  float m = -1e30f, l = 0.f;

  auto chunk4 = [&](int j0, float b0, float b1, float b2, float b3) {
    float s[4] = {b0, b1, b2, b3};
    const float* kr = kb + (size_t)j0 * HDIM;
    #pragma unroll
    for (int cc = 0; cc < 4; ++cc) {
      float acc = 0.f;
      const float4* k4 = (const float4*)(kr + cc*HDIM);
      #pragma unroll
      for (int i = 0; i < 16; ++i) {
        float4 kv = k4[i];
        acc += q[4*i+0]*kv.x + q[4*i+1]*kv.y + q[4*i+2]*kv.z + q[4*i+3]*kv.w;
      }
      s[cc] += acc;
    }
    const float cm = fmaxf(fmaxf(s[0], s[1]), fmaxf(s[2], s[3]));
    const float mn = fmaxf(m, cm);
    const float sc = __expf(m - mn);
    float p0 = __expf(s[0]-mn), p1 = __expf(s[1]-mn);
    float p2 = __expf(s[2]-mn), p3 = __expf(s[3]-mn);
    l = l * sc + (p0 + p1 + p2 + p3);
    const float* vr = vb + (size_t)j0 * HDIM;
    const float4* v0 = (const float4*)vr;
    const float4* v1 = (const float4*)(vr + HDIM);
    const float4* v2 = (const float4*)(vr + 2*HDIM);
    const float4* v3 = (const float4*)(vr + 3*HDIM);
    #pragma unroll
    for (int i = 0; i < 16; ++i) {
      float4 a = v0[i], b = v1[i], c = v2[i], d = v3[i];
      o[4*i+0] = o[4*i+0]*sc + p0*a.x + p1*b.x + p2*c.x + p3*d.x;
      o[4*i+1] = o[4*i+1]*sc + p0*a.y + p1*b.y + p2*c.y + p3*d.y;
      o[4*i+2] = o[4*i+2]*sc + p0*a.z + p1*b.z + p2*c.z + p3*d.z;
      o[4*i+3] = o[4*i+3]*sc + p0*a.w + p1*b.w + p2*c.w + p3*d.w;
    }
    m = mn;
  };

  { // cls column (j=0), no bias
    float s0 = 0.f;
    const float4* k4 = (const float4*)kb;
    #pragma unroll
    for (int i = 0; i < 16; ++i) {
      float4 kv = k4[i];
      s0 += q[4*i+0]*kv.x + q[4*i+1]*kv.y + q[4*i+2]*kv.z + q[4*i+3]*kv.w;
    }
    const float mn = fmaxf(m, s0);
    const float sc = __expf(m - mn);
    const float pp = __expf(s0 - mn);
    l = l * sc + pp;
    const float4* v4 = (const float4*)vb;
    #pragma unroll
    for (int i = 0; i < 16; ++i) {
      float4 vv = v4[i];
      o[4*i+0] = o[4*i+0]*sc + pp*vv.x;
      o[4*i+1] = o[4*i+1]*sc + pp*vv.y;
      o[4*i+2] = o[4*i+2]*sc + pp*vv.z;
      o[4*i+3] = o[4*i+3]*sc + pp*vv.w;
    }
    m = mn;
  }

  if (n > 0) {
    const float* rh = relh + (size_t)(by * 3136 + (n - 1)) * 28;
    const float* rw = relw + (size_t)(by * 3136 + (n - 1)) * 28;
    #pragma unroll 1
    for (int kh = 0; kh < 28; ++kh) {
      const float rhv = rh[kh];
      #pragma unroll 1
      for (int kwc = 0; kwc < 7; ++kwc) {
        float4 rw4 = ((const float4*)rw)[kwc];
        chunk4(1 + kh*28 + kwc*4, rhv + rw4.x, rhv + rw4.y, rhv + rw4.z, rhv + rw4.w);
      }
    }
  } else {
    #pragma unroll 1
    for (int jc = 0; jc < 196; ++jc) chunk4(1 + jc*4, 0.f, 0.f, 0.f, 0.f);
  }

  const float inv = 1.f / l;
  const bool body = (n > 0);
  float* op = outp + ((size_t)(by >> 3) * NQ + n) * 512 + (size_t)(by & 7) * 64;
  #pragma unroll
  for (int i = 0; i < 16; ++i) {
    float4 t;
    t.x = o[4*i+0]*inv; t.y = o[4*i+1]*inv;
    t.z = o[4*i+2]*inv; t.w = o[4*i+3]*inv;
    if (body) {   // residual: pooled q (un-scale the 0.125)
      t.x += q[4*i+0]*8.f; t.y += q[4*i+1]*8.f;
      t.z += q[4*i+2]*8.f; t.w += q[4*i+3]*8.f;
    }
    ((float4*)op)[i] = t;
  }
}

// ---------------------------------------------------------------------------
extern "C" void kernel_launch(void* const* d_in, const int* in_sizes, int n_in,
                              void* d_out, int out_size, void* d_ws, size_t ws_size,
                              hipStream_t stream) {
  const float* x        = (const float*)d_in[0];
  const float* qkv_w    = (const float*)d_in[1];
  const float* qkv_b    = (const float*)d_in[2];
  const float* proj_w   = (const float*)d_in[3];
  const float* proj_b   = (const float*)d_in[4];
  const float* pool_q_w = (const float*)d_in[5];
  const float* pool_k_w = (const float*)d_in[6];
  const float* pool_v_w = (const float*)d_in[7];
  const float* lnq_w    = (const float*)d_in[8];
  const float* lnq_b    = (const float*)d_in[9];
  const float* lnk_w    = (const float*)d_in[10];
  const float* lnk_b    = (const float*)d_in[11];
  const float* lnv_w    = (const float*)d_in[12];
  const float* lnv_b    = (const float*)d_in[13];
  const float* rel_pos_h = (const float*)d_in[14];
  const float* rel_pos_w = (const float*)d_in[15];

  // workspace layout (bytes)
  constexpr size_t E1       = (size_t)BB*NHH*NQ*HDIM;       // 12,849,152 elems
  constexpr size_t QKV_B    = 3*E1*2;                       // bf16
  constexpr size_t QP_B     = E1*4;
  constexpr size_t KVP_B    = (size_t)BB*NHH*NKV*HDIM*4;
  constexpr size_t REL_B    = (size_t)BB*NHH*3136*28*4;
  char* ws = (char*)d_ws;
  bf16*  qkv_raw = (bf16*)(ws);
  float* q_p     = (float*)(ws + QKV_B);
  float* k_p     = (float*)(ws + QKV_B + QP_B);
  float* v_p     = (float*)(ws + QKV_B + QP_B + KVP_B);
  float* rel_h   = (float*)(ws + QKV_B + QP_B + 2*KVP_B);
  float* rel_w   = (float*)(ws + QKV_B + QP_B + 2*KVP_B + REL_B);
  float* attn_out = (float*)(ws);   // reuse qkv_raw region (consumed by pools)

  // 1) QKV GEMM -> bf16 scatter (which,b,y,tok,c)
  dim3 g1(DIM3/64, (MROWS + 63)/64);
  gemm_bt_kernel<0><<<g1, 256, 0, stream>>>(x, qkv_w, qkv_b, (void*)qkv_raw, MROWS);

  // 2) pool + LN
  pool_ln_kernel<<<(64*NQ)/4,  256, 0, stream>>>(qkv_raw,          q_p, pool_q_w, lnq_w, lnq_b, 1, 56, NQ);
  pool_ln_kernel<<<(64*NKV)/4, 256, 0, stream>>>(qkv_raw + E1,     k_p, pool_k_w, lnk_w, lnk_b, 2, 28, NKV);
  pool_ln_kernel<<<(64*NKV)/4, 256, 0, stream>>>(qkv_raw + 2*E1,   v_p, pool_v_w, lnv_w, lnv_b, 2, 28, NKV);

  // 3) rel bias dot products
  relbias_kernel<<<(64*3136)/4, 256, 0, stream>>>(q_p, rel_pos_h, rel_pos_w, rel_h, rel_w);

  // 4) attention (+bias, softmax, PV, residual) -> (B,N,512) f32
  dim3 g4((NQ + 255)/256, 64);
  attn_kernel<<<g4, 256, 0, stream>>>(q_p, k_p, v_p, rel_h, rel_w, attn_out);

  // 5) proj GEMM -> d_out f32
  dim3 g5(512/64, (MROWS + 63)/64);
  gemm_bt_kernel<1><<<g5, 256, 0, stream>>>(attn_out, proj_w, proj_b, d_out, MROWS);
}

// Round 2
// 903.367 us; speedup vs baseline: 3.6835x; 3.6835x over previous
//
#include <hip/hip_runtime.h>
#include <hip/hip_bf16.h>
#include <cstdint>
#include <cstddef>

#define BB 8
#define NHH 8
#define NQ 3137      // 56*56+1
#define NKV 785      // 28*28+1
#define HDIM 64
#define MROWS (BB*NQ)   // 25096
#define SCALE 0.125f

typedef unsigned short ushort_t;
typedef __attribute__((ext_vector_type(8))) short s16x8;   // 8 bf16 (4 VGPR)
typedef __attribute__((ext_vector_type(4))) float f32x4;

__device__ __forceinline__ float bf2f(ushort_t u) {
  union { unsigned int i; float f; } v; v.i = ((unsigned int)u) << 16; return v.f;
}
__device__ __forceinline__ ushort_t f2bf(float f) {
  union { float f; unsigned int i; } v; v.f = f;
  unsigned int r = v.i + 0x7fffu + ((v.i >> 16) & 1u);   // RNE
  return (ushort_t)(r >> 16);
}

// ---------------------------------------------------------------------------
// f32 -> bf16 cast, 4 elems/thread (all sizes are multiples of 4)
// ---------------------------------------------------------------------------
__global__ __launch_bounds__(256) void cast_bf16_kernel(
    const float* __restrict__ in, ushort_t* __restrict__ outp, int n4) {
  const int i = blockIdx.x * 256 + threadIdx.x;
  if (i >= n4) return;
  const float4 v = ((const float4*)in)[i];
  ushort_t o[4] = { f2bf(v.x), f2bf(v.y), f2bf(v.z), f2bf(v.w) };
  *(uint2*)(outp + (size_t)i * 4) = *(const uint2*)o;
}

// ---------------------------------------------------------------------------
// bf16 MFMA GEMM: C = A(M,512) @ W(N,512)^T + bias.  128x128 tile, BK=32,
// 4 waves (each 64x64), 4x4 frags of 16x16x32.  EPI 0: bf16 scatter into
// qkv_raw[(which,b,y,tok,c)].  EPI 1: f32 store out[m*512+n].
// ---------------------------------------------------------------------------
template<int EPI>
__global__ __launch_bounds__(256) void mfma_gemm_bt(
    const ushort_t* __restrict__ A, const ushort_t* __restrict__ W,
    const float* __restrict__ bias, void* __restrict__ outp, int M) {
  __shared__ ushort_t As[128][40];   // +8 pad: 80B row stride
  __shared__ ushort_t Bs[128][40];
  const int tid = threadIdx.x;
  const int l = tid & 63, w = tid >> 6;
  const int wr = w >> 1, wc = w & 1;
  const int lrow = l & 15, lk = l >> 4;
  const int m0 = blockIdx.y * 128, n0 = blockIdx.x * 128;
  const int srow = tid >> 2, sch = tid & 3;   // staging: row 0..63, 4x16B chunks
  const int mA0 = m0 + srow      < M ? m0 + srow      : M - 1;
  const int mA1 = m0 + 64 + srow < M ? m0 + 64 + srow : M - 1;
  const size_t ar0 = (size_t)mA0 * 512, ar1 = (size_t)mA1 * 512;
  const size_t br0 = (size_t)(n0 + srow) * 512, br1 = (size_t)(n0 + 64 + srow) * 512;
  f32x4 acc[4][4];
  #pragma unroll
  for (int i = 0; i < 4; ++i) {
    #pragma unroll
    for (int j = 0; j < 4; ++j) acc[i][j] = (f32x4){0.f, 0.f, 0.f, 0.f};
  }
  for (int k0 = 0; k0 < 512; k0 += 32) {
    const uint4 a0 = *(const uint4*)(A + ar0 + k0 + sch * 8);
    const uint4 a1 = *(const uint4*)(A + ar1 + k0 + sch * 8);
    const uint4 b0 = *(const uint4*)(W + br0 + k0 + sch * 8);
    const uint4 b1 = *(const uint4*)(W + br1 + k0 + sch * 8);
    __syncthreads();
    *(uint4*)(&As[srow][sch * 8])      = a0;
    *(uint4*)(&As[64 + srow][sch * 8]) = a1;
    *(uint4*)(&Bs[srow][sch * 8])      = b0;
    *(uint4*)(&Bs[64 + srow][sch * 8]) = b1;
    __syncthreads();
    s16x8 af[4], bfr[4];
    #pragma unroll
    for (int mi = 0; mi < 4; ++mi)
      af[mi] = *(const s16x8*)(&As[wr * 64 + mi * 16 + lrow][lk * 8]);
    #pragma unroll
    for (int ni = 0; ni < 4; ++ni)
      bfr[ni] = *(const s16x8*)(&Bs[wc * 64 + ni * 16 + lrow][lk * 8]);
    #pragma unroll
    for (int mi = 0; mi < 4; ++mi) {
      #pragma unroll
      for (int ni = 0; ni < 4; ++ni)
        acc[mi][ni] = __builtin_amdgcn_mfma_f32_16x16x32_bf16(
            af[mi], bfr[ni], acc[mi][ni], 0, 0, 0);
    }
  }
  #pragma unroll
  for (int mi = 0; mi < 4; ++mi) {
    #pragma unroll
    for (int r = 0; r < 4; ++r) {
      const int m = m0 + wr * 64 + mi * 16 + 4 * lk + r;  // C row = (l>>4)*4+reg
      if (m >= M) continue;
      #pragma unroll
      for (int ni = 0; ni < 4; ++ni) {
        const int n = n0 + wc * 64 + ni * 16 + lrow;      // C col = l&15
        const float v = acc[mi][ni][r] + bias[n];
        if (EPI == 0) {
          const int which = n >> 9, y = (n >> 6) & 7, c = n & 63;
          const int b_ = m / NQ, tok = m - b_ * NQ;
          ((ushort_t*)outp)[((((size_t)which * BB + b_) * NHH + y) * NQ + tok) * HDIM + c] = f2bf(v);
        } else {
          ((float*)outp)[(size_t)m * 512 + n] = v;
        }
      }
    }
  }
}

// ---------------------------------------------------------------------------
// Depthwise 3x3 pool (zero-pad 1) + LayerNorm over HD=64.  bf16 in/out,
// f32 math.  One wave per output row.
// ---------------------------------------------------------------------------
__global__ __launch_bounds__(256) void pool_ln_kernel(
    const ushort_t* __restrict__ in, ushort_t* __restrict__ outp,
    const float* __restrict__ cw, const float* __restrict__ lnw,
    const float* __restrict__ lnb, int stride, int OW, int R) {
  const int tid = threadIdx.x;
  const int c = tid & 63;
  const int rid = blockIdx.x * 4 + (tid >> 6);
  const int by = rid / R;
  const int n = rid - by * R;
  const ushort_t* ibase = in + (size_t)by * NQ * HDIM;
  float val;
  if (n == 0) {
    val = bf2f(ibase[c]);
  } else {
    const int p = n - 1;
    const int ho = p / OW, wo = p - ho * OW;
    float s = 0.f;
    #pragma unroll
    for (int dh = 0; dh < 3; ++dh) {
      const int hh = ho * stride + dh - 1;
      if (hh < 0 || hh >= 56) continue;
      #pragma unroll
      for (int dw = 0; dw < 3; ++dw) {
        const int ww = wo * stride + dw - 1;
        if (ww < 0 || ww >= 56) continue;
        s += cw[c * 9 + dh * 3 + dw] * bf2f(ibase[(size_t)(1 + hh * 56 + ww) * HDIM + c]);
      }
    }
    val = s;
  }
  float sum = val, sq = val * val;
  #pragma unroll
  for (int off = 32; off > 0; off >>= 1) {
    sum += __shfl_xor(sum, off);
    sq  += __shfl_xor(sq,  off);
  }
  const float mean = sum * (1.f / 64.f);
  const float var  = sq * (1.f / 64.f) - mean * mean;
  const float rs = rsqrtf(var + 1e-6f);
  outp[(size_t)rid * HDIM + c] = f2bf((val - mean) * rs * lnw[c] + lnb[c]);
}

// ---------------------------------------------------------------------------
// rel_h / rel_w dot products (f32 out), q read as bf16.
// ---------------------------------------------------------------------------
__global__ __launch_bounds__(256) void relbias_kernel(
    const ushort_t* __restrict__ qb, const float* __restrict__ rph,
    const float* __restrict__ rpw, float* __restrict__ relh,
    float* __restrict__ relw) {
  __shared__ float qs[4][64];
  const int tid = threadIdx.x;
  const int l = tid & 63;
  const int wv = tid >> 6;
  const int r = blockIdx.x * 4 + wv;
  const int by = r / 3136;
  const int p = r - by * 3136;
  const int h = p / 56, w = p - h * 56;
  qs[wv][l] = bf2f(qb[((size_t)by * NQ + 1 + p) * HDIM + l]);
  __syncthreads();
  const float* rp;
  if (l < 28)                 rp = rph + (size_t)(h - 2 * l + 54) * 64;
  else if (l >= 32 && l < 60) rp = rpw + (size_t)(w - 2 * (l - 32) + 54) * 64;
  else                        rp = rph;
  float dot = 0.f;
  #pragma unroll
  for (int i = 0; i < 16; ++i) {
    float4 rv = ((const float4*)rp)[i];
    dot += qs[wv][4*i+0]*rv.x + qs[wv][4*i+1]*rv.y
         + qs[wv][4*i+2]*rv.z + qs[wv][4*i+3]*rv.w;
  }
  if (l < 28)                 relh[(size_t)r * 28 + l]        = dot;
  else if (l >= 32 && l < 60) relw[(size_t)r * 28 + (l - 32)] = dot;
}

// ---------------------------------------------------------------------------
// Flash-style MFMA attention.  Block = 4 waves, 64 q rows of one (b,head).
// Wave w: q rows qt0+w*16..+15.  25 iters x 32 k-cols (j>=785 masked).
// ---------------------------------------------------------------------------
__global__ __launch_bounds__(256) void attn_mfma_kernel(
    const ushort_t* __restrict__ qb, const ushort_t* __restrict__ kb,
    const ushort_t* __restrict__ vbuf, const float* __restrict__ relh,
    const float* __restrict__ relw, ushort_t* __restrict__ outp) {
  __shared__ ushort_t Kl[32][72];      // K rows x 64ch, stride 144B (2-way)
  __shared__ ushort_t VT[64][40];      // V^T: ch x 32 k-rows, stride 80B
  __shared__ ushort_t Pl[4][16][40];   // per-wave P relayout tile
  __shared__ float RH[64][28];
  __shared__ float RW[64][28];
  const int tid = threadIdx.x;
  const int l = tid & 63, w = tid >> 6;
  const int lrow = l & 15, lk = l >> 4;
  const int by = blockIdx.y;
  const int qt0 = blockIdx.x * 64;
  // stage rel-bias rows for this block's 64 q rows (zeros for cls/invalid)
  #pragma unroll
  for (int i = 0; i < 7; ++i) {
    const int idx = tid + i * 256;           // 64*28 = 1792 = 7*256
    const int r = idx / 28, c = idx - 28 * r;
    const int n = qt0 + r;
    float vh = 0.f, vw = 0.f;
    if (n >= 1 && n < NQ) {
      const size_t base = ((size_t)by * 3136 + (n - 1)) * 28 + c;
      vh = relh[base]; vw = relw[base];
    }
    RH[r][c] = vh; RW[r][c] = vw;
  }
  // Q A-frags (loop-invariant): row = l%16, k = (l/16)*8+i
  const int nq = qt0 + w * 16 + lrow;
  const ushort_t* qrow = qb + ((size_t)by * NQ + (nq < NQ ? nq : 0)) * HDIM;
  const s16x8 qa0 = *(const s16x8*)(qrow + lk * 8);
  const s16x8 qa1 = *(const s16x8*)(qrow + 32 + lk * 8);
  f32x4 o[4];
  #pragma unroll
  for (int cb = 0; cb < 4; ++cb) o[cb] = (f32x4){0.f, 0.f, 0.f, 0.f};
  float mr[4] = {-1e30f, -1e30f, -1e30f, -1e30f};
  float lr[4] = {0.f, 0.f, 0.f, 0.f};
  const int srow = tid >> 3, schunk = tid & 7;   // K/V staging
  __syncthreads();
  #pragma unroll 1
  for (int it = 0; it < 25; ++it) {
    const int j0 = it * 32;
    const int j = j0 + srow;
    uint4 kd = make_uint4(0u,0u,0u,0u), vd = make_uint4(0u,0u,0u,0u);
    if (j < NKV) {
      kd = *(const uint4*)(kb   + ((size_t)by * NKV + j) * HDIM + schunk * 8);
      vd = *(const uint4*)(vbuf + ((size_t)by * NKV + j) * HDIM + schunk * 8);
    }
    __syncthreads();                       // prev iter's LDS reads done
    *(uint4*)(&Kl[srow][schunk * 8]) = kd;
    const ushort_t* vdp = (const ushort_t*)&vd;
    #pragma unroll
    for (int e = 0; e < 8; ++e) VT[schunk * 8 + e][srow] = vdp[e];
    __syncthreads();
    // S = Q K^T (two 16-col halves, K-dim 64 = 2 mfma each)
    const f32x4 z = (f32x4){0.f, 0.f, 0.f, 0.f};
    const s16x8 b00 = *(const s16x8*)(&Kl[lrow][lk * 8]);
    const s16x8 b01 = *(const s16x8*)(&Kl[lrow][32 + lk * 8]);
    f32x4 s0 = __builtin_amdgcn_mfma_f32_16x16x32_bf16(qa1, b01, z, 0, 0, 0);
    s0 = __builtin_amdgcn_mfma_f32_16x16x32_bf16(qa0, b00, s0, 0, 0, 0);
    const s16x8 b10 = *(const s16x8*)(&Kl[16 + lrow][lk * 8]);
    const s16x8 b11 = *(const s16x8*)(&Kl[16 + lrow][32 + lk * 8]);
    f32x4 s1 = __builtin_amdgcn_mfma_f32_16x16x32_bf16(qa1, b11, z, 0, 0, 0);
    s1 = __builtin_amdgcn_mfma_f32_16x16x32_bf16(qa0, b10, s1, 0, 0, 0);
    // online softmax per reg-row (rows 4*lk+r, cols = lrow within 16-group)
    const int jA = j0 + lrow;          // always < 785
    const int jB = jA + 16;
    int khA = 0, kwA = 0, khB = 0, kwB = 0;
    const bool bA = (jA >= 1);
    const bool mB = (jB < NKV);
    const bool bB = (jB >= 1) && mB;
    if (bA) { khA = (jA - 1) / 28; kwA = (jA - 1) - 28 * khA; }
    if (bB) { khB = (jB - 1) / 28; kwB = (jB - 1) - 28 * khB; }
    float sc_[4];
    #pragma unroll
    for (int r = 0; r < 4; ++r) {
      const int i = w * 16 + 4 * lk + r;
      const float v0 = s0[r] * SCALE + (bA ? RH[i][khA] + RW[i][kwA] : 0.f);
      const float v1 = mB ? (s1[r] * SCALE + (bB ? RH[i][khB] + RW[i][kwB] : 0.f))
                          : -1e30f;
      float cm = fmaxf(v0, v1);
      cm = fmaxf(cm, __shfl_xor(cm, 1));
      cm = fmaxf(cm, __shfl_xor(cm, 2));
      cm = fmaxf(cm, __shfl_xor(cm, 4));
      cm = fmaxf(cm, __shfl_xor(cm, 8));
      const float mn = fmaxf(mr[r], cm);
      const float sc = __expf(mr[r] - mn);
      const float p0 = __expf(v0 - mn);
      const float p1 = __expf(v1 - mn);
      float ps = p0 + p1;
      ps += __shfl_xor(ps, 1);
      ps += __shfl_xor(ps, 2);
      ps += __shfl_xor(ps, 4);
      ps += __shfl_xor(ps, 8);
      lr[r] = lr[r] * sc + ps;
      mr[r] = mn;
      sc_[r] = sc;
      Pl[w][4 * lk + r][lrow]      = f2bf(p0);
      Pl[w][4 * lk + r][16 + lrow] = f2bf(p1);
    }
    #pragma unroll
    for (int cb = 0; cb < 4; ++cb) {
      #pragma unroll
      for (int r = 0; r < 4; ++r) o[cb][r] *= sc_[r];
    }
    __builtin_amdgcn_sched_barrier(0);   // keep P writes before pa read
    const s16x8 pa = *(const s16x8*)(&Pl[w][lrow][lk * 8]);
    #pragma unroll
    for (int cb = 0; cb < 4; ++cb) {
      const s16x8 vf = *(const s16x8*)(&VT[cb * 16 + lrow][lk * 8]);
      o[cb] = __builtin_amdgcn_mfma_f32_16x16x32_bf16(pa, vf, o[cb], 0, 0, 0);
    }
  }
  // epilogue: normalize, +residual (pooled q), store bf16 (B,N,512)
  float inv[4];
  #pragma unroll
  for (int r = 0; r < 4; ++r) inv[r] = 1.f / lr[r];
  const int b_ = by >> 3, y_ = by & 7;
  #pragma unroll
  for (int r = 0; r < 4; ++r) {
    const int n = qt0 + w * 16 + 4 * lk + r;
    if (n >= NQ) continue;
    #pragma unroll
    for (int cb = 0; cb < 4; ++cb) {
      const int c = cb * 16 + lrow;
      float val = o[cb][r] * inv[r];
      if (n > 0) val += bf2f(qb[((size_t)by * NQ + n) * HDIM + c]);
      outp[((size_t)b_ * NQ + n) * 512 + (size_t)y_ * 64 + c] = f2bf(val);
    }
  }
}

// ---------------------------------------------------------------------------
extern "C" void kernel_launch(void* const* d_in, const int* in_sizes, int n_in,
                              void* d_out, int out_size, void* d_ws, size_t ws_size,
                              hipStream_t stream) {
  const float* x        = (const float*)d_in[0];
  const float* qkv_w    = (const float*)d_in[1];
  const float* qkv_b    = (const float*)d_in[2];
  const float* proj_w   = (const float*)d_in[3];
  const float* proj_b   = (const float*)d_in[4];
  const float* pool_q_w = (const float*)d_in[5];
  const float* pool_k_w = (const float*)d_in[6];
  const float* pool_v_w = (const float*)d_in[7];
  const float* lnq_w    = (const float*)d_in[8];
  const float* lnq_b    = (const float*)d_in[9];
  const float* lnk_w    = (const float*)d_in[10];
  const float* lnk_b    = (const float*)d_in[11];
  const float* lnv_w    = (const float*)d_in[12];
  const float* lnv_b    = (const float*)d_in[13];
  const float* rel_pos_h = (const float*)d_in[14];
  const float* rel_pos_w = (const float*)d_in[15];

  constexpr size_t E1 = (size_t)BB * NHH * NQ * HDIM;   // 12,849,152
  constexpr size_t EKV = (size_t)BB * NHH * NKV * HDIM; // 3,215,360
  char* ws = (char*)d_ws;
  size_t off = 0;
  ushort_t* x_bf     = (ushort_t*)(ws + off); off += (size_t)MROWS * 512 * 2;
  ushort_t* qkvw_bf  = (ushort_t*)(ws + off); off += (size_t)1536 * 512 * 2;
  ushort_t* projw_bf = (ushort_t*)(ws + off); off += (size_t)512 * 512 * 2;
  ushort_t* qkv_raw  = (ushort_t*)(ws + off); off += 3 * E1 * 2;
  ushort_t* q_bf     = (ushort_t*)(ws + off); off += E1 * 2;
  ushort_t* k_bf     = (ushort_t*)(ws + off); off += EKV * 2;
  ushort_t* v_bf     = (ushort_t*)(ws + off); off += EKV * 2;
  float*    rel_h    = (float*)(ws + off);    off += (size_t)64 * 3136 * 28 * 4;
  float*    rel_w    = (float*)(ws + off);    off += (size_t)64 * 3136 * 28 * 4;
  ushort_t* attn_bf  = qkv_raw;   // reuse (raw consumed by pools before attn)

  // 0) casts to bf16
  cast_bf16_kernel<<<(MROWS * 512 / 4 + 255) / 256, 256, 0, stream>>>(x, x_bf, MROWS * 512 / 4);
  cast_bf16_kernel<<<768, 256, 0, stream>>>(qkv_w, qkvw_bf, 1536 * 512 / 4);
  cast_bf16_kernel<<<256, 256, 0, stream>>>(proj_w, projw_bf, 512 * 512 / 4);

  // 1) QKV GEMM (bf16 MFMA) -> qkv_raw scatter
  mfma_gemm_bt<0><<<dim3(12, 197), 256, 0, stream>>>(x_bf, qkvw_bf, qkv_b, (void*)qkv_raw, MROWS);

  // 2) pool + LN (bf16 out)
  pool_ln_kernel<<<(64 * NQ) / 4,  256, 0, stream>>>(qkv_raw,          q_bf, pool_q_w, lnq_w, lnq_b, 1, 56, NQ);
  pool_ln_kernel<<<(64 * NKV) / 4, 256, 0, stream>>>(qkv_raw + E1,     k_bf, pool_k_w, lnk_w, lnk_b, 2, 28, NKV);
  pool_ln_kernel<<<(64 * NKV) / 4, 256, 0, stream>>>(qkv_raw + 2 * E1, v_bf, pool_v_w, lnv_w, lnv_b, 2, 28, NKV);

  // 3) rel bias dot products
  relbias_kernel<<<(64 * 3136) / 4, 256, 0, stream>>>(q_bf, rel_pos_h, rel_pos_w, rel_h, rel_w);

  // 4) MFMA flash attention (+bias, softmax, PV, residual) -> bf16 (B,N,512)
  attn_mfma_kernel<<<dim3(50, 64), 256, 0, stream>>>(q_bf, k_bf, v_bf, rel_h, rel_w, attn_bf);

  // 5) proj GEMM (bf16 MFMA) -> d_out f32
  mfma_gemm_bt<1><<<dim3(4, 197), 256, 0, stream>>>(attn_bf, projw_bf, proj_b, d_out, MROWS);
}

// Round 3
// 611.840 us; speedup vs baseline: 5.4386x; 1.4765x over previous
//
#include <hip/hip_runtime.h>
#include <hip/hip_bf16.h>
#include <cstdint>
#include <cstddef>

#define BB 8
#define NHH 8
#define NQ 3137      // 56*56+1
#define NKV 785      // 28*28+1
#define HDIM 64
#define MROWS (BB*NQ)   // 25096
#define SCALE 0.125f

typedef unsigned short ushort_t;
typedef __attribute__((ext_vector_type(8))) short s16x8;   // 8 bf16 (4 VGPR)
typedef __attribute__((ext_vector_type(4))) float f32x4;

__device__ __forceinline__ float bf2f(ushort_t u) {
  union { unsigned int i; float f; } v; v.i = ((unsigned int)u) << 16; return v.f;
}
__device__ __forceinline__ ushort_t f2bf(float f) {
  union { float f; unsigned int i; } v; v.f = f;
  unsigned int r = v.i + 0x7fffu + ((v.i >> 16) & 1u);   // RNE
  return (ushort_t)(r >> 16);
}

// ---------------------------------------------------------------------------
// f32 -> bf16 cast, 4 elems/thread (all sizes are multiples of 4)
// ---------------------------------------------------------------------------
__global__ __launch_bounds__(256) void cast_bf16_kernel(
    const float* __restrict__ in, ushort_t* __restrict__ outp, int n4) {
  const int i = blockIdx.x * 256 + threadIdx.x;
  if (i >= n4) return;
  const float4 v = ((const float4*)in)[i];
  ushort_t o[4] = { f2bf(v.x), f2bf(v.y), f2bf(v.z), f2bf(v.w) };
  *(uint2*)(outp + (size_t)i * 4) = *(const uint2*)o;
}

// ---------------------------------------------------------------------------
// bf16 MFMA GEMM: C = A(M,512) @ W(N,512)^T + bias.  128x128 tile, BK=32,
// 4 waves (each 64x64), 4x4 frags of 16x16x32.  EPI 0: bf16 scatter into
// qkv_raw[(which,b,y,tok,c)].  EPI 1: f32 store out[m*512+n].
// ---------------------------------------------------------------------------
template<int EPI>
__global__ __launch_bounds__(256) void mfma_gemm_bt(
    const ushort_t* __restrict__ A, const ushort_t* __restrict__ W,
    const float* __restrict__ bias, void* __restrict__ outp, int M) {
  __shared__ ushort_t As[128][40];   // +8 pad: 80B row stride
  __shared__ ushort_t Bs[128][40];
  const int tid = threadIdx.x;
  const int l = tid & 63, w = tid >> 6;
  const int wr = w >> 1, wc = w & 1;
  const int lrow = l & 15, lk = l >> 4;
  const int m0 = blockIdx.y * 128, n0 = blockIdx.x * 128;
  const int srow = tid >> 2, sch = tid & 3;   // staging: row 0..63, 4x16B chunks
  const int mA0 = m0 + srow      < M ? m0 + srow      : M - 1;
  const int mA1 = m0 + 64 + srow < M ? m0 + 64 + srow : M - 1;
  const size_t ar0 = (size_t)mA0 * 512, ar1 = (size_t)mA1 * 512;
  const size_t br0 = (size_t)(n0 + srow) * 512, br1 = (size_t)(n0 + 64 + srow) * 512;
  f32x4 acc[4][4];
  #pragma unroll
  for (int i = 0; i < 4; ++i) {
    #pragma unroll
    for (int j = 0; j < 4; ++j) acc[i][j] = (f32x4){0.f, 0.f, 0.f, 0.f};
  }
  for (int k0 = 0; k0 < 512; k0 += 32) {
    const uint4 a0 = *(const uint4*)(A + ar0 + k0 + sch * 8);
    const uint4 a1 = *(const uint4*)(A + ar1 + k0 + sch * 8);
    const uint4 b0 = *(const uint4*)(W + br0 + k0 + sch * 8);
    const uint4 b1 = *(const uint4*)(W + br1 + k0 + sch * 8);
    __syncthreads();
    *(uint4*)(&As[srow][sch * 8])      = a0;
    *(uint4*)(&As[64 + srow][sch * 8]) = a1;
    *(uint4*)(&Bs[srow][sch * 8])      = b0;
    *(uint4*)(&Bs[64 + srow][sch * 8]) = b1;
    __syncthreads();
    s16x8 af[4], bfr[4];
    #pragma unroll
    for (int mi = 0; mi < 4; ++mi)
      af[mi] = *(const s16x8*)(&As[wr * 64 + mi * 16 + lrow][lk * 8]);
    #pragma unroll
    for (int ni = 0; ni < 4; ++ni)
      bfr[ni] = *(const s16x8*)(&Bs[wc * 64 + ni * 16 + lrow][lk * 8]);
    #pragma unroll
    for (int mi = 0; mi < 4; ++mi) {
      #pragma unroll
      for (int ni = 0; ni < 4; ++ni)
        acc[mi][ni] = __builtin_amdgcn_mfma_f32_16x16x32_bf16(
            af[mi], bfr[ni], acc[mi][ni], 0, 0, 0);
    }
  }
  #pragma unroll
  for (int mi = 0; mi < 4; ++mi) {
    #pragma unroll
    for (int r = 0; r < 4; ++r) {
      const int m = m0 + wr * 64 + mi * 16 + 4 * lk + r;  // C row = (l>>4)*4+reg
      if (m >= M) continue;
      #pragma unroll
      for (int ni = 0; ni < 4; ++ni) {
        const int n = n0 + wc * 64 + ni * 16 + lrow;      // C col = l&15
        const float v = acc[mi][ni][r] + bias[n];
        if (EPI == 0) {
          const int which = n >> 9, y = (n >> 6) & 7, c = n & 63;
          const int b_ = m / NQ, tok = m - b_ * NQ;
          ((ushort_t*)outp)[((((size_t)which * BB + b_) * NHH + y) * NQ + tok) * HDIM + c] = f2bf(v);
        } else {
          ((float*)outp)[(size_t)m * 512 + n] = v;
        }
      }
    }
  }
}

// ---------------------------------------------------------------------------
// Depthwise 3x3 pool (zero-pad 1) + LayerNorm over HD=64.  bf16 in/out,
// f32 math.  One wave per output row.
// ---------------------------------------------------------------------------
__global__ __launch_bounds__(256) void pool_ln_kernel(
    const ushort_t* __restrict__ in, ushort_t* __restrict__ outp,
    const float* __restrict__ cw, const float* __restrict__ lnw,
    const float* __restrict__ lnb, int stride, int OW, int R) {
  const int tid = threadIdx.x;
  const int c = tid & 63;
  const int rid = blockIdx.x * 4 + (tid >> 6);
  const int by = rid / R;
  const int n = rid - by * R;
  const ushort_t* ibase = in + (size_t)by * NQ * HDIM;
  float val;
  if (n == 0) {
    val = bf2f(ibase[c]);
  } else {
    const int p = n - 1;
    const int ho = p / OW, wo = p - ho * OW;
    float s = 0.f;
    #pragma unroll
    for (int dh = 0; dh < 3; ++dh) {
      const int hh = ho * stride + dh - 1;
      if (hh < 0 || hh >= 56) continue;
      #pragma unroll
      for (int dw = 0; dw < 3; ++dw) {
        const int ww = wo * stride + dw - 1;
        if (ww < 0 || ww >= 56) continue;
        s += cw[c * 9 + dh * 3 + dw] * bf2f(ibase[(size_t)(1 + hh * 56 + ww) * HDIM + c]);
      }
    }
    val = s;
  }
  float sum = val, sq = val * val;
  #pragma unroll
  for (int off = 32; off > 0; off >>= 1) {
    sum += __shfl_xor(sum, off);
    sq  += __shfl_xor(sq,  off);
  }
  const float mean = sum * (1.f / 64.f);
  const float var  = sq * (1.f / 64.f) - mean * mean;
  const float rs = rsqrtf(var + 1e-6f);
  outp[(size_t)rid * HDIM + c] = f2bf((val - mean) * rs * lnw[c] + lnb[c]);
}

// ---------------------------------------------------------------------------
// MFMA rel-bias.  blockIdx.z = 0: rel_h (batch over h), 1: rel_w (batch over
// w).  For fixed hw, C(3584 x 28) = Q(3584 x 64) @ T(28 x 64)^T where rows
// are ordered r = by*56 + other, T row kh = tab[hw - 2*kh + 54].
// Block = 4 waves x 64 rows = 256 rows; grid.x = 14, grid.y = 56 (hw).
// ---------------------------------------------------------------------------
__global__ __launch_bounds__(256) void relbias_mfma_kernel(
    const ushort_t* __restrict__ qb, const float* __restrict__ rph,
    const float* __restrict__ rpw, float* __restrict__ relh,
    float* __restrict__ relw) {
  const int tid = threadIdx.x;
  const int l = tid & 63, w = tid >> 6;
  const int lrow = l & 15, lk = l >> 4;
  const int hw = blockIdx.y;
  const int mode = blockIdx.z;
  const int r0 = blockIdx.x * 256 + w * 64;
  const float* tab = mode ? rpw : rph;
  float* outp = mode ? relw : relh;
  // B-frags: col kh = ni*16 + (l&15); k = k0*32 + (l>>4)*8 + i (c index)
  s16x8 bfr[2][2];
  #pragma unroll
  for (int ni = 0; ni < 2; ++ni) {
    const int kh = ni * 16 + lrow;
    int trow = hw - 2 * kh + 54;
    if (trow < 0) trow = 0;            // kh>=28 garbage, masked on store
    const float* tr = tab + (size_t)trow * 64 + lk * 8;
    #pragma unroll
    for (int k0 = 0; k0 < 2; ++k0) {
      const float4 t0 = *(const float4*)(tr + k0 * 32);
      const float4 t1 = *(const float4*)(tr + k0 * 32 + 4);
      s16x8 bb;
      bb[0] = (short)f2bf(t0.x); bb[1] = (short)f2bf(t0.y);
      bb[2] = (short)f2bf(t0.z); bb[3] = (short)f2bf(t0.w);
      bb[4] = (short)f2bf(t1.x); bb[5] = (short)f2bf(t1.y);
      bb[6] = (short)f2bf(t1.z); bb[7] = (short)f2bf(t1.w);
      bfr[ni][k0] = bb;
    }
  }
  // A-frags: row rA = r0 + mi*16 + (l&15) -> (by, other); token from mode
  s16x8 af[4][2];
  #pragma unroll
  for (int mi = 0; mi < 4; ++mi) {
    const int rA = r0 + mi * 16 + lrow;
    const int by = rA / 56, oth = rA - 56 * by;
    const int tok = mode ? (1 + oth * 56 + hw) : (1 + hw * 56 + oth);
    const ushort_t* qp = qb + ((size_t)by * NQ + tok) * HDIM + lk * 8;
    af[mi][0] = *(const s16x8*)(qp);
    af[mi][1] = *(const s16x8*)(qp + 32);
  }
  f32x4 acc[4][2];
  #pragma unroll
  for (int mi = 0; mi < 4; ++mi) {
    #pragma unroll
    for (int ni = 0; ni < 2; ++ni) acc[mi][ni] = (f32x4){0.f, 0.f, 0.f, 0.f};
  }
  #pragma unroll
  for (int k0 = 0; k0 < 2; ++k0) {
    #pragma unroll
    for (int mi = 0; mi < 4; ++mi) {
      #pragma unroll
      for (int ni = 0; ni < 2; ++ni)
        acc[mi][ni] = __builtin_amdgcn_mfma_f32_16x16x32_bf16(
            af[mi][k0], bfr[ni][k0], acc[mi][ni], 0, 0, 0);
    }
  }
  // store: C row = r0 + mi*16 + 4*(l>>4) + reg, col kh = ni*16 + (l&15)
  #pragma unroll
  for (int mi = 0; mi < 4; ++mi) {
    #pragma unroll
    for (int r = 0; r < 4; ++r) {
      const int row = r0 + mi * 16 + 4 * lk + r;
      const int by = row / 56, oth = row - 56 * by;
      const int p = mode ? (oth * 56 + hw) : (hw * 56 + oth);
      float* orow = outp + ((size_t)by * 3136 + p) * 28;
      #pragma unroll
      for (int ni = 0; ni < 2; ++ni) {
        const int kh = ni * 16 + lrow;
        if (kh < 28) orow[kh] = acc[mi][ni][r];
      }
    }
  }
}

// ---------------------------------------------------------------------------
// Flash-style MFMA attention.  Block = 4 waves, 64 q rows of one (b,head).
// Wave w: q rows qt0+w*16..+15.  25 iters x 32 k-cols (j>=785 masked).
// ---------------------------------------------------------------------------
__global__ __launch_bounds__(256) void attn_mfma_kernel(
    const ushort_t* __restrict__ qb, const ushort_t* __restrict__ kb,
    const ushort_t* __restrict__ vbuf, const float* __restrict__ relh,
    const float* __restrict__ relw, ushort_t* __restrict__ outp) {
  __shared__ ushort_t Kl[32][72];      // K rows x 64ch, stride 144B (2-way)
  __shared__ ushort_t VT[64][40];      // V^T: ch x 32 k-rows, stride 80B
  __shared__ ushort_t Pl[4][16][40];   // per-wave P relayout tile
  __shared__ float RH[64][28];
  __shared__ float RW[64][28];
  const int tid = threadIdx.x;
  const int l = tid & 63, w = tid >> 6;
  const int lrow = l & 15, lk = l >> 4;
  const int by = blockIdx.y;
  const int qt0 = blockIdx.x * 64;
  // stage rel-bias rows for this block's 64 q rows (zeros for cls/invalid)
  #pragma unroll
  for (int i = 0; i < 7; ++i) {
    const int idx = tid + i * 256;           // 64*28 = 1792 = 7*256
    const int r = idx / 28, c = idx - 28 * r;
    const int n = qt0 + r;
    float vh = 0.f, vw = 0.f;
    if (n >= 1 && n < NQ) {
      const size_t base = ((size_t)by * 3136 + (n - 1)) * 28 + c;
      vh = relh[base]; vw = relw[base];
    }
    RH[r][c] = vh; RW[r][c] = vw;
  }
  // Q A-frags (loop-invariant): row = l%16, k = (l/16)*8+i
  const int nq = qt0 + w * 16 + lrow;
  const ushort_t* qrow = qb + ((size_t)by * NQ + (nq < NQ ? nq : 0)) * HDIM;
  const s16x8 qa0 = *(const s16x8*)(qrow + lk * 8);
  const s16x8 qa1 = *(const s16x8*)(qrow + 32 + lk * 8);
  f32x4 o[4];
  #pragma unroll
  for (int cb = 0; cb < 4; ++cb) o[cb] = (f32x4){0.f, 0.f, 0.f, 0.f};
  float mr[4] = {-1e30f, -1e30f, -1e30f, -1e30f};
  float lr[4] = {0.f, 0.f, 0.f, 0.f};
  const int srow = tid >> 3, schunk = tid & 7;   // K/V staging
  __syncthreads();
  #pragma unroll 1
  for (int it = 0; it < 25; ++it) {
    const int j0 = it * 32;
    const int j = j0 + srow;
    uint4 kd = make_uint4(0u,0u,0u,0u), vd = make_uint4(0u,0u,0u,0u);
    if (j < NKV) {
      kd = *(const uint4*)(kb   + ((size_t)by * NKV + j) * HDIM + schunk * 8);
      vd = *(const uint4*)(vbuf + ((size_t)by * NKV + j) * HDIM + schunk * 8);
    }
    __syncthreads();                       // prev iter's LDS reads done
    *(uint4*)(&Kl[srow][schunk * 8]) = kd;
    const ushort_t* vdp = (const ushort_t*)&vd;
    #pragma unroll
    for (int e = 0; e < 8; ++e) VT[schunk * 8 + e][srow] = vdp[e];
    __syncthreads();
    // S = Q K^T (two 16-col halves, K-dim 64 = 2 mfma each)
    const f32x4 z = (f32x4){0.f, 0.f, 0.f, 0.f};
    const s16x8 b00 = *(const s16x8*)(&Kl[lrow][lk * 8]);
    const s16x8 b01 = *(const s16x8*)(&Kl[lrow][32 + lk * 8]);
    f32x4 s0 = __builtin_amdgcn_mfma_f32_16x16x32_bf16(qa1, b01, z, 0, 0, 0);
    s0 = __builtin_amdgcn_mfma_f32_16x16x32_bf16(qa0, b00, s0, 0, 0, 0);
    const s16x8 b10 = *(const s16x8*)(&Kl[16 + lrow][lk * 8]);
    const s16x8 b11 = *(const s16x8*)(&Kl[16 + lrow][32 + lk * 8]);
    f32x4 s1 = __builtin_amdgcn_mfma_f32_16x16x32_bf16(qa1, b11, z, 0, 0, 0);
    s1 = __builtin_amdgcn_mfma_f32_16x16x32_bf16(qa0, b10, s1, 0, 0, 0);
    // online softmax per reg-row (rows 4*lk+r, cols = lrow within 16-group)
    const int jA = j0 + lrow;          // always < 785
    const int jB = jA + 16;
    int khA = 0, kwA = 0, khB = 0, kwB = 0;
    const bool bA = (jA >= 1);
    const bool mB = (jB < NKV);
    const bool bB = (jB >= 1) && mB;
    if (bA) { khA = (jA - 1) / 28; kwA = (jA - 1) - 28 * khA; }
    if (bB) { khB = (jB - 1) / 28; kwB = (jB - 1) - 28 * khB; }
    float sc_[4];
    #pragma unroll
    for (int r = 0; r < 4; ++r) {
      const int i = w * 16 + 4 * lk + r;
      const float v0 = s0[r] * SCALE + (bA ? RH[i][khA] + RW[i][kwA] : 0.f);
      const float v1 = mB ? (s1[r] * SCALE + (bB ? RH[i][khB] + RW[i][kwB] : 0.f))
                          : -1e30f;
      float cm = fmaxf(v0, v1);
      cm = fmaxf(cm, __shfl_xor(cm, 1));
      cm = fmaxf(cm, __shfl_xor(cm, 2));
      cm = fmaxf(cm, __shfl_xor(cm, 4));
      cm = fmaxf(cm, __shfl_xor(cm, 8));
      const float mn = fmaxf(mr[r], cm);
      const float sc = __expf(mr[r] - mn);
      const float p0 = __expf(v0 - mn);
      const float p1 = __expf(v1 - mn);
      float ps = p0 + p1;
      ps += __shfl_xor(ps, 1);
      ps += __shfl_xor(ps, 2);
      ps += __shfl_xor(ps, 4);
      ps += __shfl_xor(ps, 8);
      lr[r] = lr[r] * sc + ps;
      mr[r] = mn;
      sc_[r] = sc;
      Pl[w][4 * lk + r][lrow]      = f2bf(p0);
      Pl[w][4 * lk + r][16 + lrow] = f2bf(p1);
    }
    #pragma unroll
    for (int cb = 0; cb < 4; ++cb) {
      #pragma unroll
      for (int r = 0; r < 4; ++r) o[cb][r] *= sc_[r];
    }
    __builtin_amdgcn_sched_barrier(0);   // keep P writes before pa read
    const s16x8 pa = *(const s16x8*)(&Pl[w][lrow][lk * 8]);
    #pragma unroll
    for (int cb = 0; cb < 4; ++cb) {
      const s16x8 vf = *(const s16x8*)(&VT[cb * 16 + lrow][lk * 8]);
      o[cb] = __builtin_amdgcn_mfma_f32_16x16x32_bf16(pa, vf, o[cb], 0, 0, 0);
    }
  }
  // epilogue: normalize, +residual (pooled q), store bf16 (B,N,512)
  float inv[4];
  #pragma unroll
  for (int r = 0; r < 4; ++r) inv[r] = 1.f / lr[r];
  const int b_ = by >> 3, y_ = by & 7;
  #pragma unroll
  for (int r = 0; r < 4; ++r) {
    const int n = qt0 + w * 16 + 4 * lk + r;
    if (n >= NQ) continue;
    #pragma unroll
    for (int cb = 0; cb < 4; ++cb) {
      const int c = cb * 16 + lrow;
      float val = o[cb][r] * inv[r];
      if (n > 0) val += bf2f(qb[((size_t)by * NQ + n) * HDIM + c]);
      outp[((size_t)b_ * NQ + n) * 512 + (size_t)y_ * 64 + c] = f2bf(val);
    }
  }
}

// ---------------------------------------------------------------------------
extern "C" void kernel_launch(void* const* d_in, const int* in_sizes, int n_in,
                              void* d_out, int out_size, void* d_ws, size_t ws_size,
                              hipStream_t stream) {
  const float* x        = (const float*)d_in[0];
  const float* qkv_w    = (const float*)d_in[1];
  const float* qkv_b    = (const float*)d_in[2];
  const float* proj_w   = (const float*)d_in[3];
  const float* proj_b   = (const float*)d_in[4];
  const float* pool_q_w = (const float*)d_in[5];
  const float* pool_k_w = (const float*)d_in[6];
  const float* pool_v_w = (const float*)d_in[7];
  const float* lnq_w    = (const float*)d_in[8];
  const float* lnq_b    = (const float*)d_in[9];
  const float* lnk_w    = (const float*)d_in[10];
  const float* lnk_b    = (const float*)d_in[11];
  const float* lnv_w    = (const float*)d_in[12];
  const float* lnv_b    = (const float*)d_in[13];
  const float* rel_pos_h = (const float*)d_in[14];
  const float* rel_pos_w = (const float*)d_in[15];

  constexpr size_t E1 = (size_t)BB * NHH * NQ * HDIM;   // 12,849,152
  constexpr size_t EKV = (size_t)BB * NHH * NKV * HDIM; // 3,215,360
  char* ws = (char*)d_ws;
  size_t off = 0;
  ushort_t* x_bf     = (ushort_t*)(ws + off); off += (size_t)MROWS * 512 * 2;
  ushort_t* qkvw_bf  = (ushort_t*)(ws + off); off += (size_t)1536 * 512 * 2;
  ushort_t* projw_bf = (ushort_t*)(ws + off); off += (size_t)512 * 512 * 2;
  ushort_t* qkv_raw  = (ushort_t*)(ws + off); off += 3 * E1 * 2;
  ushort_t* q_bf     = (ushort_t*)(ws + off); off += E1 * 2;
  ushort_t* k_bf     = (ushort_t*)(ws + off); off += EKV * 2;
  ushort_t* v_bf     = (ushort_t*)(ws + off); off += EKV * 2;
  float*    rel_h    = (float*)(ws + off);    off += (size_t)64 * 3136 * 28 * 4;
  float*    rel_w    = (float*)(ws + off);    off += (size_t)64 * 3136 * 28 * 4;
  ushort_t* attn_bf  = qkv_raw;   // reuse (raw consumed by pools before attn)

  // 0) casts to bf16
  cast_bf16_kernel<<<(MROWS * 512 / 4 + 255) / 256, 256, 0, stream>>>(x, x_bf, MROWS * 512 / 4);
  cast_bf16_kernel<<<768, 256, 0, stream>>>(qkv_w, qkvw_bf, 1536 * 512 / 4);
  cast_bf16_kernel<<<256, 256, 0, stream>>>(proj_w, projw_bf, 512 * 512 / 4);

  // 1) QKV GEMM (bf16 MFMA) -> qkv_raw scatter
  mfma_gemm_bt<0><<<dim3(12, 197), 256, 0, stream>>>(x_bf, qkvw_bf, qkv_b, (void*)qkv_raw, MROWS);

  // 2) pool + LN (bf16 out)
  pool_ln_kernel<<<(64 * NQ) / 4,  256, 0, stream>>>(qkv_raw,          q_bf, pool_q_w, lnq_w, lnq_b, 1, 56, NQ);
  pool_ln_kernel<<<(64 * NKV) / 4, 256, 0, stream>>>(qkv_raw + E1,     k_bf, pool_k_w, lnk_w, lnk_b, 2, 28, NKV);
  pool_ln_kernel<<<(64 * NKV) / 4, 256, 0, stream>>>(qkv_raw + 2 * E1, v_bf, pool_v_w, lnv_w, lnv_b, 2, 28, NKV);

  // 3) rel bias via MFMA (z=0: rel_h over h; z=1: rel_w over w)
  relbias_mfma_kernel<<<dim3(14, 56, 2), 256, 0, stream>>>(q_bf, rel_pos_h, rel_pos_w, rel_h, rel_w);

  // 4) MFMA flash attention (+bias, softmax, PV, residual) -> bf16 (B,N,512)
  attn_mfma_kernel<<<dim3(50, 64), 256, 0, stream>>>(q_bf, k_bf, v_bf, rel_h, rel_w, attn_bf);

  // 5) proj GEMM (bf16 MFMA) -> d_out f32
  mfma_gemm_bt<1><<<dim3(4, 197), 256, 0, stream>>>(attn_bf, projw_bf, proj_b, d_out, MROWS);
}

// Round 4
// 479.440 us; speedup vs baseline: 6.9405x; 1.2762x over previous
//
#include <hip/hip_runtime.h>
#include <hip/hip_bf16.h>
#include <cstdint>
#include <cstddef>

#define BB 8
#define NHH 8
#define NQ 3137      // 56*56+1
#define NKV 785      // 28*28+1
#define HDIM 64
#define MROWS (BB*NQ)   // 25096
#define SCALE 0.125f
#define VTP 832         // padded v^T row length

typedef unsigned short ushort_t;
typedef __attribute__((ext_vector_type(8))) short s16x8;   // 8 bf16 (4 VGPR)
typedef __attribute__((ext_vector_type(4))) float f32x4;
typedef __attribute__((ext_vector_type(16))) float f32x16;

__device__ __forceinline__ float bf2f(ushort_t u) {
  union { unsigned int i; float f; } v; v.i = ((unsigned int)u) << 16; return v.f;
}
__device__ __forceinline__ ushort_t f2bf(float f) {
  union { float f; unsigned int i; } v; v.f = f;
  unsigned int r = v.i + 0x7fffu + ((v.i >> 16) & 1u);   // RNE
  return (ushort_t)(r >> 16);
}
__device__ __forceinline__ unsigned int cvt_pk_bf16(float lo, float hi) {
  unsigned int r;
  asm("v_cvt_pk_bf16_f32 %0, %1, %2" : "=v"(r) : "v"(lo), "v"(hi));
  return r;
}
// swizzled 16B fragment read from a [64][64]-bf16 LDS tile (128B rows)
__device__ __forceinline__ s16x8 lds_frag(const ushort_t* base, int row, int slot) {
  const char* p = (const char*)base + row * 128 + (((slot ^ (row & 7)) & 7) << 4);
  return *(const s16x8*)p;
}

// ---------------------------------------------------------------------------
// f32 -> bf16 cast, 4 elems/thread
// ---------------------------------------------------------------------------
__global__ __launch_bounds__(256) void cast_bf16_kernel(
    const float* __restrict__ in, ushort_t* __restrict__ outp, int n4) {
  const int i = blockIdx.x * 256 + threadIdx.x;
  if (i >= n4) return;
  const float4 v = ((const float4*)in)[i];
  ushort_t o[4] = { f2bf(v.x), f2bf(v.y), f2bf(v.z), f2bf(v.w) };
  *(uint2*)(outp + (size_t)i * 4) = *(const uint2*)o;
}

// ---------------------------------------------------------------------------
// bf16 MFMA GEMM: C = A(M,512) @ W(N,512)^T + bias.  128x128 tile, BK=32.
// ---------------------------------------------------------------------------
template<int EPI>
__global__ __launch_bounds__(256) void mfma_gemm_bt(
    const ushort_t* __restrict__ A, const ushort_t* __restrict__ W,
    const float* __restrict__ bias, void* __restrict__ outp, int M) {
  __shared__ ushort_t As[128][40];
  __shared__ ushort_t Bs[128][40];
  const int tid = threadIdx.x;
  const int l = tid & 63, w = tid >> 6;
  const int wr = w >> 1, wc = w & 1;
  const int lrow = l & 15, lk = l >> 4;
  const int m0 = blockIdx.y * 128, n0 = blockIdx.x * 128;
  const int srow = tid >> 2, sch = tid & 3;
  const int mA0 = m0 + srow      < M ? m0 + srow      : M - 1;
  const int mA1 = m0 + 64 + srow < M ? m0 + 64 + srow : M - 1;
  const size_t ar0 = (size_t)mA0 * 512, ar1 = (size_t)mA1 * 512;
  const size_t br0 = (size_t)(n0 + srow) * 512, br1 = (size_t)(n0 + 64 + srow) * 512;
  f32x4 acc[4][4];
  #pragma unroll
  for (int i = 0; i < 4; ++i) {
    #pragma unroll
    for (int j = 0; j < 4; ++j) acc[i][j] = (f32x4){0.f, 0.f, 0.f, 0.f};
  }
  for (int k0 = 0; k0 < 512; k0 += 32) {
    const uint4 a0 = *(const uint4*)(A + ar0 + k0 + sch * 8);
    const uint4 a1 = *(const uint4*)(A + ar1 + k0 + sch * 8);
    const uint4 b0 = *(const uint4*)(W + br0 + k0 + sch * 8);
    const uint4 b1 = *(const uint4*)(W + br1 + k0 + sch * 8);
    __syncthreads();
    *(uint4*)(&As[srow][sch * 8])      = a0;
    *(uint4*)(&As[64 + srow][sch * 8]) = a1;
    *(uint4*)(&Bs[srow][sch * 8])      = b0;
    *(uint4*)(&Bs[64 + srow][sch * 8]) = b1;
    __syncthreads();
    s16x8 af[4], bfr[4];
    #pragma unroll
    for (int mi = 0; mi < 4; ++mi)
      af[mi] = *(const s16x8*)(&As[wr * 64 + mi * 16 + lrow][lk * 8]);
    #pragma unroll
    for (int ni = 0; ni < 4; ++ni)
      bfr[ni] = *(const s16x8*)(&Bs[wc * 64 + ni * 16 + lrow][lk * 8]);
    #pragma unroll
    for (int mi = 0; mi < 4; ++mi) {
      #pragma unroll
      for (int ni = 0; ni < 4; ++ni)
        acc[mi][ni] = __builtin_amdgcn_mfma_f32_16x16x32_bf16(
            af[mi], bfr[ni], acc[mi][ni], 0, 0, 0);
    }
  }
  #pragma unroll
  for (int mi = 0; mi < 4; ++mi) {
    #pragma unroll
    for (int r = 0; r < 4; ++r) {
      const int m = m0 + wr * 64 + mi * 16 + 4 * lk + r;
      if (m >= M) continue;
      #pragma unroll
      for (int ni = 0; ni < 4; ++ni) {
        const int n = n0 + wc * 64 + ni * 16 + lrow;
        const float v = acc[mi][ni][r] + bias[n];
        if (EPI == 0) {
          const int which = n >> 9, y = (n >> 6) & 7, c = n & 63;
          const int b_ = m / NQ, tok = m - b_ * NQ;
          ((ushort_t*)outp)[((((size_t)which * BB + b_) * NHH + y) * NQ + tok) * HDIM + c] = f2bf(v);
        } else {
          ((float*)outp)[(size_t)m * 512 + n] = v;
        }
      }
    }
  }
}

// ---------------------------------------------------------------------------
// Depthwise 3x3 pool + LayerNorm over HD=64.  bf16 in/out, f32 math.
// ---------------------------------------------------------------------------
__global__ __launch_bounds__(256) void pool_ln_kernel(
    const ushort_t* __restrict__ in, ushort_t* __restrict__ outp,
    const float* __restrict__ cw, const float* __restrict__ lnw,
    const float* __restrict__ lnb, int stride, int OW, int R) {
  const int tid = threadIdx.x;
  const int c = tid & 63;
  const int rid = blockIdx.x * 4 + (tid >> 6);
  const int by = rid / R;
  const int n = rid - by * R;
  const ushort_t* ibase = in + (size_t)by * NQ * HDIM;
  float val;
  if (n == 0) {
    val = bf2f(ibase[c]);
  } else {
    const int p = n - 1;
    const int ho = p / OW, wo = p - ho * OW;
    float s = 0.f;
    #pragma unroll
    for (int dh = 0; dh < 3; ++dh) {
      const int hh = ho * stride + dh - 1;
      if (hh < 0 || hh >= 56) continue;
      #pragma unroll
      for (int dw = 0; dw < 3; ++dw) {
        const int ww = wo * stride + dw - 1;
        if (ww < 0 || ww >= 56) continue;
        s += cw[c * 9 + dh * 3 + dw] * bf2f(ibase[(size_t)(1 + hh * 56 + ww) * HDIM + c]);
      }
    }
    val = s;
  }
  float sum = val, sq = val * val;
  #pragma unroll
  for (int off = 32; off > 0; off >>= 1) {
    sum += __shfl_xor(sum, off);
    sq  += __shfl_xor(sq,  off);
  }
  const float mean = sum * (1.f / 64.f);
  const float var  = sq * (1.f / 64.f) - mean * mean;
  const float rs = rsqrtf(var + 1e-6f);
  outp[(size_t)rid * HDIM + c] = f2bf((val - mean) * rs * lnw[c] + lnb[c]);
}

// ---------------------------------------------------------------------------
// V (row-major per head) -> V^T (64 channels x VTP cols), zero-padded cols.
// ---------------------------------------------------------------------------
__global__ __launch_bounds__(256) void transpose_v_kernel(
    const ushort_t* __restrict__ vin, ushort_t* __restrict__ vtout) {
  __shared__ ushort_t T[64][65];
  const int tid = threadIdx.x;
  const int by = blockIdx.y;
  const int n0 = blockIdx.x * 64;
  #pragma unroll
  for (int half = 0; half < 2; ++half) {
    const int idx = tid + half * 256;
    const int r = idx >> 3, s = idx & 7;
    const int n = n0 + r;
    uint4 d = make_uint4(0u, 0u, 0u, 0u);
    if (n < NKV) d = *(const uint4*)(vin + ((size_t)by * NKV + n) * HDIM + s * 8);
    const ushort_t* dp = (const ushort_t*)&d;
    #pragma unroll
    for (int e = 0; e < 8; ++e) T[r][s * 8 + e] = dp[e];
  }
  __syncthreads();
  #pragma unroll
  for (int half = 0; half < 2; ++half) {
    const int idx = tid + half * 256;
    const int c = idx >> 3, g = idx & 7;
    ushort_t pk[8];
    #pragma unroll
    for (int e = 0; e < 8; ++e) pk[e] = T[g * 8 + e][c];
    *(uint4*)(vtout + ((size_t)by * 64 + c) * VTP + n0 + g * 8) = *(const uint4*)pk;
  }
}

// ---------------------------------------------------------------------------
// MFMA rel-bias (unchanged from round 3).
// ---------------------------------------------------------------------------
__global__ __launch_bounds__(256) void relbias_mfma_kernel(
    const ushort_t* __restrict__ qb, const float* __restrict__ rph,
    const float* __restrict__ rpw, float* __restrict__ relh,
    float* __restrict__ relw) {
  const int tid = threadIdx.x;
  const int l = tid & 63, w = tid >> 6;
  const int lrow = l & 15, lk = l >> 4;
  const int hw = blockIdx.y;
  const int mode = blockIdx.z;
  const int r0 = blockIdx.x * 256 + w * 64;
  const float* tab = mode ? rpw : rph;
  float* outp = mode ? relw : relh;
  s16x8 bfr[2][2];
  #pragma unroll
  for (int ni = 0; ni < 2; ++ni) {
    const int kh = ni * 16 + lrow;
    int trow = hw - 2 * kh + 54;
    if (trow < 0) trow = 0;
    const float* tr = tab + (size_t)trow * 64 + lk * 8;
    #pragma unroll
    for (int k0 = 0; k0 < 2; ++k0) {
      const float4 t0 = *(const float4*)(tr + k0 * 32);
      const float4 t1 = *(const float4*)(tr + k0 * 32 + 4);
      s16x8 bb;
      bb[0] = (short)f2bf(t0.x); bb[1] = (short)f2bf(t0.y);
      bb[2] = (short)f2bf(t0.z); bb[3] = (short)f2bf(t0.w);
      bb[4] = (short)f2bf(t1.x); bb[5] = (short)f2bf(t1.y);
      bb[6] = (short)f2bf(t1.z); bb[7] = (short)f2bf(t1.w);
      bfr[ni][k0] = bb;
    }
  }
  s16x8 af[4][2];
  #pragma unroll
  for (int mi = 0; mi < 4; ++mi) {
    const int rA = r0 + mi * 16 + lrow;
    const int by = rA / 56, oth = rA - 56 * by;
    const int tok = mode ? (1 + oth * 56 + hw) : (1 + hw * 56 + oth);
    const ushort_t* qp = qb + ((size_t)by * NQ + tok) * HDIM + lk * 8;
    af[mi][0] = *(const s16x8*)(qp);
    af[mi][1] = *(const s16x8*)(qp + 32);
  }
  f32x4 acc[4][2];
  #pragma unroll
  for (int mi = 0; mi < 4; ++mi) {
    #pragma unroll
    for (int ni = 0; ni < 2; ++ni) acc[mi][ni] = (f32x4){0.f, 0.f, 0.f, 0.f};
  }
  #pragma unroll
  for (int k0 = 0; k0 < 2; ++k0) {
    #pragma unroll
    for (int mi = 0; mi < 4; ++mi) {
      #pragma unroll
      for (int ni = 0; ni < 2; ++ni)
        acc[mi][ni] = __builtin_amdgcn_mfma_f32_16x16x32_bf16(
            af[mi][k0], bfr[ni][k0], acc[mi][ni], 0, 0, 0);
    }
  }
  #pragma unroll
  for (int mi = 0; mi < 4; ++mi) {
    #pragma unroll
    for (int r = 0; r < 4; ++r) {
      const int row = r0 + mi * 16 + 4 * lk + r;
      const int by = row / 56, oth = row - 56 * by;
      const int p = mode ? (oth * 56 + hw) : (hw * 56 + oth);
      float* orow = outp + ((size_t)by * 3136 + p) * 28;
      #pragma unroll
      for (int ni = 0; ni < 2; ++ni) {
        const int kh = ni * 16 + lrow;
        if (kh < 28) orow[kh] = acc[mi][ni][r];
      }
    }
  }
}

// ---------------------------------------------------------------------------
// Flash attention, 32x32 MFMA, swapped operands (S^T and O^T), XOR-swizzled
// LDS.  Block = 4 waves x 32 q rows = 128 q; 13 iters x 64 k.
// ---------------------------------------------------------------------------
__global__ __launch_bounds__(256) void attn_mfma32_kernel(
    const ushort_t* __restrict__ qb, const ushort_t* __restrict__ kb,
    const ushort_t* __restrict__ vt, const float* __restrict__ relh,
    const float* __restrict__ relw, ushort_t* __restrict__ outp) {
  __shared__ ushort_t Kl[64 * 64];
  __shared__ ushort_t Vl[64 * 64];
  __shared__ float RHl[128][29];
  __shared__ float RWl[128][29];
  const int tid = threadIdx.x;
  const int l = tid & 63, w = tid >> 6;
  const int h = l >> 5, q5 = l & 31;
  const int by = blockIdx.y;
  const int qt0 = blockIdx.x * 128;
  const int qloc = w * 32 + q5;
  const int qglob = qt0 + qloc;
  const int qcl = qglob < NQ ? qglob : NQ - 1;
  // stage rel-bias rows (zeros for cls / out-of-range)
  for (int i = tid; i < 128 * 28; i += 256) {
    const int r = i / 28, c = i - 28 * r;
    const int n = qt0 + r;
    float vh = 0.f, vw = 0.f;
    if (n >= 1 && n < NQ) {
      const size_t bofs = ((size_t)by * 3136 + (n - 1)) * 28 + c;
      vh = relh[bofs]; vw = relw[bofs];
    }
    RHl[r][c] = vh; RWl[r][c] = vw;
  }
  // Q fragments (loop-invariant): B-frag col = l&31 = q, k(c) = cb*16+8h+i
  const ushort_t* qrow = qb + ((size_t)by * NQ + qcl) * HDIM;
  s16x8 qf[4];
  #pragma unroll
  for (int cb = 0; cb < 4; ++cb)
    qf[cb] = *(const s16x8*)(qrow + cb * 16 + h * 8);
  f32x16 ot0, ot1;
  #pragma unroll
  for (int i = 0; i < 16; ++i) { ot0[i] = 0.f; ot1[i] = 0.f; }
  float mr = -1e30f, lr = 0.f;
  const int srow = tid >> 3, sslot = tid & 7;
  #pragma unroll 1
  for (int it = 0; it < 13; ++it) {
    const int j0 = it * 64;
    int jA = j0 + srow;      if (jA > NKV - 1) jA = NKV - 1;
    int jB = j0 + 32 + srow; if (jB > NKV - 1) jB = NKV - 1;
    const uint4 kd0 = *(const uint4*)(kb + ((size_t)by * NKV + jA) * HDIM + sslot * 8);
    const uint4 kd1 = *(const uint4*)(kb + ((size_t)by * NKV + jB) * HDIM + sslot * 8);
    const uint4 vd0 = *(const uint4*)(vt + ((size_t)by * 64 + srow) * VTP + j0 + sslot * 8);
    const uint4 vd1 = *(const uint4*)(vt + ((size_t)by * 64 + srow + 32) * VTP + j0 + sslot * 8);
    __syncthreads();
    *(uint4*)((char*)Kl + srow * 128 + (((sslot ^ (srow & 7)) & 7) << 4)) = kd0;
    *(uint4*)((char*)Kl + (srow + 32) * 128 + (((sslot ^ ((srow + 32) & 7)) & 7) << 4)) = kd1;
    *(uint4*)((char*)Vl + srow * 128 + (((sslot ^ (srow & 7)) & 7) << 4)) = vd0;
    *(uint4*)((char*)Vl + (srow + 32) * 128 + (((sslot ^ ((srow + 32) & 7)) & 7) << 4)) = vd1;
    __syncthreads();
    // S^T = K @ Q^T : two 32-k subtiles, D col = q
    f32x16 st0, st1;
    #pragma unroll
    for (int i = 0; i < 16; ++i) { st0[i] = 0.f; st1[i] = 0.f; }
    #pragma unroll
    for (int cb = 0; cb < 4; ++cb) {
      st0 = __builtin_amdgcn_mfma_f32_32x32x16_bf16(
          lds_frag(Kl, q5, cb * 2 + h), qf[cb], st0, 0, 0, 0);
      st1 = __builtin_amdgcn_mfma_f32_32x32x16_bf16(
          lds_frag(Kl, 32 + q5, cb * 2 + h), qf[cb], st1, 0, 0, 0);
    }
    // scores + bias + mask
    float pa[16], pb[16];
    auto sval = [&](float (&pv)[16], const f32x16& st, int kt) {
      const int jbase = j0 + kt * 32 + 4 * h;
      int jc0 = jbase - 1; if (jc0 < 0) jc0 = 0;
      int khlo = jc0 / 28; if (khlo > 27) khlo = 27;
      const int khhi = khlo < 27 ? khlo + 1 : 27;
      const float rh_lo = RHl[qloc][khlo];
      const float rh_hi = RHl[qloc][khhi];
      const int jswitch = (khlo + 1) * 28 + 1;
      #pragma unroll
      for (int r = 0; r < 16; ++r) {
        const int klocal = (r & 3) + 8 * (r >> 2) + 4 * h;
        const int j = j0 + kt * 32 + klocal;
        const bool valid = j < NKV;
        const bool hasb = (j >= 1) && valid;
        const bool hi = (j >= jswitch);
        const float rhv = hi ? rh_hi : rh_lo;
        const int khv = hi ? khhi : khlo;
        int jc = j - 1; if (jc < 0) jc = 0;
        int kw = jc - 28 * khv;
        if (kw > 27) kw = 27; if (kw < 0) kw = 0;
        const float rwv = RWl[qloc][kw];
        const float sv = st[r] * SCALE + (hasb ? (rhv + rwv) : 0.f);
        pv[r] = valid ? sv : -1e30f;
      }
    };
    sval(pa, st0, 0);
    sval(pb, st1, 1);
    // online softmax (row = lane's q; partner lane l^32 holds other half)
    float mloc = pa[0];
    #pragma unroll
    for (int r = 1; r < 16; ++r) mloc = fmaxf(mloc, pa[r]);
    #pragma unroll
    for (int r = 0; r < 16; ++r) mloc = fmaxf(mloc, pb[r]);
    mloc = fmaxf(mloc, __shfl_xor(mloc, 32));
    const float mn = fmaxf(mr, mloc);
    const float sc = __expf(mr - mn);
    mr = mn;
    float ps = 0.f;
    #pragma unroll
    for (int r = 0; r < 16; ++r) { pa[r] = __expf(pa[r] - mn); ps += pa[r]; }
    #pragma unroll
    for (int r = 0; r < 16; ++r) { pb[r] = __expf(pb[r] - mn); ps += pb[r]; }
    ps += __shfl_xor(ps, 32);
    lr = lr * sc + ps;
    #pragma unroll
    for (int i = 0; i < 16; ++i) { ot0[i] *= sc; ot1[i] *= sc; }
    // pack P -> bf16 B-frags and accumulate O^T = V^T @ P^T
    auto pvstep = [&](const float (&pv)[16], int kt) {
      #pragma unroll
      for (int kbk = 0; kbk < 2; ++kbk) {
        const unsigned int pk01 = cvt_pk_bf16(pv[kbk * 8 + 0], pv[kbk * 8 + 1]);
        const unsigned int pk23 = cvt_pk_bf16(pv[kbk * 8 + 2], pv[kbk * 8 + 3]);
        const unsigned int pk45 = cvt_pk_bf16(pv[kbk * 8 + 4], pv[kbk * 8 + 5]);
        const unsigned int pk67 = cvt_pk_bf16(pv[kbk * 8 + 6], pv[kbk * 8 + 7]);
        const unsigned int sA = (unsigned int)__shfl_xor((int)pk01, 32);
        const unsigned int sB = (unsigned int)__shfl_xor((int)pk45, 32);
        const unsigned int sC = (unsigned int)__shfl_xor((int)pk23, 32);
        const unsigned int sD = (unsigned int)__shfl_xor((int)pk67, 32);
        int4 fw;
        fw.x = (int)(h ? sB : pk01);
        fw.y = (int)(h ? sD : pk23);
        fw.z = (int)(h ? pk45 : sA);
        fw.w = (int)(h ? pk67 : sC);
        s16x8 pf;
        __builtin_memcpy(&pf, &fw, 16);
        const int slot = kt * 4 + kbk * 2 + h;
        ot0 = __builtin_amdgcn_mfma_f32_32x32x16_bf16(
            lds_frag(Vl, q5, slot), pf, ot0, 0, 0, 0);
        ot1 = __builtin_amdgcn_mfma_f32_32x32x16_bf16(
            lds_frag(Vl, 32 + q5, slot), pf, ot1, 0, 0, 0);
      }
    };
    pvstep(pa, 0);
    pvstep(pb, 1);
  }
  // epilogue: O^T frag: lane's q = q5-based, channels c = ch*32+8*rg+4h+e
  const float inv = 1.f / lr;
  if (qglob < NQ) {
    const int b_ = by >> 3, y_ = by & 7;
    ushort_t* obase = outp + ((size_t)b_ * NQ + qglob) * 512 + (size_t)y_ * 64;
    const ushort_t* rbase = qb + ((size_t)by * NQ + qglob) * HDIM;
    #pragma unroll
    for (int ch = 0; ch < 2; ++ch) {
      #pragma unroll
      for (int rg = 0; rg < 4; ++rg) {
        const int c0 = ch * 32 + 8 * rg + 4 * h;
        float vv[4];
        #pragma unroll
        for (int e = 0; e < 4; ++e)
          vv[e] = (ch ? ot1[rg * 4 + e] : ot0[rg * 4 + e]) * inv;
        if (qglob > 0) {
          #pragma unroll
          for (int e = 0; e < 4; ++e) vv[e] += bf2f(rbase[c0 + e]);
        }
        ushort_t pk[4] = { f2bf(vv[0]), f2bf(vv[1]), f2bf(vv[2]), f2bf(vv[3]) };
        *(uint2*)(obase + c0) = *(const uint2*)pk;
      }
    }
  }
}

// ---------------------------------------------------------------------------
extern "C" void kernel_launch(void* const* d_in, const int* in_sizes, int n_in,
                              void* d_out, int out_size, void* d_ws, size_t ws_size,
                              hipStream_t stream) {
  const float* x        = (const float*)d_in[0];
  const float* qkv_w    = (const float*)d_in[1];
  const float* qkv_b    = (const float*)d_in[2];
  const float* proj_w   = (const float*)d_in[3];
  const float* proj_b   = (const float*)d_in[4];
  const float* pool_q_w = (const float*)d_in[5];
  const float* pool_k_w = (const float*)d_in[6];
  const float* pool_v_w = (const float*)d_in[7];
  const float* lnq_w    = (const float*)d_in[8];
  const float* lnq_b    = (const float*)d_in[9];
  const float* lnk_w    = (const float*)d_in[10];
  const float* lnk_b    = (const float*)d_in[11];
  const float* lnv_w    = (const float*)d_in[12];
  const float* lnv_b    = (const float*)d_in[13];
  const float* rel_pos_h = (const float*)d_in[14];
  const float* rel_pos_w = (const float*)d_in[15];

  constexpr size_t E1 = (size_t)BB * NHH * NQ * HDIM;   // 12,849,152
  constexpr size_t EKV = (size_t)BB * NHH * NKV * HDIM; // 3,215,360
  char* ws = (char*)d_ws;
  size_t off = 0;
  ushort_t* x_bf     = (ushort_t*)(ws + off); off += (size_t)MROWS * 512 * 2;
  ushort_t* qkvw_bf  = (ushort_t*)(ws + off); off += (size_t)1536 * 512 * 2;
  ushort_t* projw_bf = (ushort_t*)(ws + off); off += (size_t)512 * 512 * 2;
  ushort_t* qkv_raw  = (ushort_t*)(ws + off); off += 3 * E1 * 2;
  ushort_t* q_bf     = (ushort_t*)(ws + off); off += E1 * 2;
  ushort_t* k_bf     = (ushort_t*)(ws + off); off += EKV * 2;
  ushort_t* v_bf     = (ushort_t*)(ws + off); off += EKV * 2;
  ushort_t* v_t      = (ushort_t*)(ws + off); off += (size_t)64 * 64 * VTP * 2;
  float*    rel_h    = (float*)(ws + off);    off += (size_t)64 * 3136 * 28 * 4;
  float*    rel_w    = (float*)(ws + off);    off += (size_t)64 * 3136 * 28 * 4;
  ushort_t* attn_bf  = qkv_raw;   // reuse (raw consumed by pools before attn)

  // 0) casts to bf16
  cast_bf16_kernel<<<(MROWS * 512 / 4 + 255) / 256, 256, 0, stream>>>(x, x_bf, MROWS * 512 / 4);
  cast_bf16_kernel<<<768, 256, 0, stream>>>(qkv_w, qkvw_bf, 1536 * 512 / 4);
  cast_bf16_kernel<<<256, 256, 0, stream>>>(proj_w, projw_bf, 512 * 512 / 4);

  // 1) QKV GEMM (bf16 MFMA) -> qkv_raw scatter
  mfma_gemm_bt<0><<<dim3(12, 197), 256, 0, stream>>>(x_bf, qkvw_bf, qkv_b, (void*)qkv_raw, MROWS);

  // 2) pool + LN (bf16 out)
  pool_ln_kernel<<<(64 * NQ) / 4,  256, 0, stream>>>(qkv_raw,          q_bf, pool_q_w, lnq_w, lnq_b, 1, 56, NQ);
  pool_ln_kernel<<<(64 * NKV) / 4, 256, 0, stream>>>(qkv_raw + E1,     k_bf, pool_k_w, lnk_w, lnk_b, 2, 28, NKV);
  pool_ln_kernel<<<(64 * NKV) / 4, 256, 0, stream>>>(qkv_raw + 2 * E1, v_bf, pool_v_w, lnv_w, lnv_b, 2, 28, NKV);

  // 2b) V -> V^T (channel-major, padded cols)
  transpose_v_kernel<<<dim3(13, 64), 256, 0, stream>>>(v_bf, v_t);

  // 3) rel bias via MFMA
  relbias_mfma_kernel<<<dim3(14, 56, 2), 256, 0, stream>>>(q_bf, rel_pos_h, rel_pos_w, rel_h, rel_w);

  // 4) flash attention (32x32 MFMA, swapped) -> bf16 (B,N,512)
  attn_mfma32_kernel<<<dim3(25, 64), 256, 0, stream>>>(q_bf, k_bf, v_t, rel_h, rel_w, attn_bf);

  // 5) proj GEMM (bf16 MFMA) -> d_out f32
  mfma_gemm_bt<1><<<dim3(4, 197), 256, 0, stream>>>(attn_bf, projw_bf, proj_b, d_out, MROWS);
}

// Round 5
// 472.611 us; speedup vs baseline: 7.0407x; 1.0144x over previous
//
#include <hip/hip_runtime.h>
#include <hip/hip_bf16.h>
#include <cstdint>
#include <cstddef>

#define BB 8
#define NHH 8
#define NQ 3137      // 56*56+1
#define NKV 785      // 28*28+1
#define HDIM 64
#define AUG 128      // augmented channel count (64 q/k + 28 h + 28 w + 8 pad)
#define MROWS (BB*NQ)   // 25096
#define SCALE 0.125f
#define VTP 832         // padded v^T row length

typedef unsigned short ushort_t;
typedef __attribute__((ext_vector_type(8))) short s16x8;   // 8 bf16 (4 VGPR)
typedef __attribute__((ext_vector_type(4))) float f32x4;
typedef __attribute__((ext_vector_type(16))) float f32x16;

__device__ __forceinline__ float bf2f(ushort_t u) {
  union { unsigned int i; float f; } v; v.i = ((unsigned int)u) << 16; return v.f;
}
__device__ __forceinline__ ushort_t f2bf(float f) {
  union { float f; unsigned int i; } v; v.f = f;
  unsigned int r = v.i + 0x7fffu + ((v.i >> 16) & 1u);   // RNE
  return (ushort_t)(r >> 16);
}
__device__ __forceinline__ unsigned int cvt_pk_bf16(float lo, float hi) {
  unsigned int r;
  asm("v_cvt_pk_bf16_f32 %0, %1, %2" : "=v"(r) : "v"(lo), "v"(hi));
  return r;
}
// swizzled 16B fragment read, 128B rows (8 slots)
__device__ __forceinline__ s16x8 lds_frag8(const ushort_t* base, int row, int slot) {
  const char* p = (const char*)base + row * 128 + (((slot ^ (row & 7)) & 7) << 4);
  return *(const s16x8*)p;
}
// swizzled 16B fragment read, 256B rows (16 slots)
__device__ __forceinline__ s16x8 lds_frag16(const ushort_t* base, int row, int slot) {
  const char* p = (const char*)base + row * 256 + (((slot ^ (row & 15)) & 15) << 4);
  return *(const s16x8*)p;
}

// ---------------------------------------------------------------------------
// bf16 MFMA GEMM: C = A(M,512) @ W(N,512)^T + bias.  128x128 tile, BK=32.
// AF32/WF32: source is f32, cast in-register during staging.
// EPI 0: bf16 scatter into qkv_raw[(which,b,y,tok,c)].  EPI 1: f32 store.
// ---------------------------------------------------------------------------
template<int EPI, bool AF32, bool WF32>
__global__ __launch_bounds__(256) void mfma_gemm_bt(
    const void* __restrict__ Ap, const void* __restrict__ Wp,
    const float* __restrict__ bias, void* __restrict__ outp, int M) {
  __shared__ ushort_t As[128][40];
  __shared__ ushort_t Bs[128][40];
  const int tid = threadIdx.x;
  const int l = tid & 63, w = tid >> 6;
  const int wr = w >> 1, wc = w & 1;
  const int lrow = l & 15, lk = l >> 4;
  const int m0 = blockIdx.y * 128, n0 = blockIdx.x * 128;
  const int srow = tid >> 2, sch = tid & 3;
  const int mA0 = m0 + srow      < M ? m0 + srow      : M - 1;
  const int mA1 = m0 + 64 + srow < M ? m0 + 64 + srow : M - 1;
  const size_t ar0 = (size_t)mA0 * 512, ar1 = (size_t)mA1 * 512;
  const size_t br0 = (size_t)(n0 + srow) * 512, br1 = (size_t)(n0 + 64 + srow) * 512;
  const ushort_t* Ab = (const ushort_t*)Ap;
  const float*    Af = (const float*)Ap;
  const ushort_t* Wb = (const ushort_t*)Wp;
  const float*    Wf = (const float*)Wp;
  auto ld8 = [&](const ushort_t* pb, const float* pf, size_t ofs, bool f32) -> uint4 {
    if (!f32) return *(const uint4*)(pb + ofs);
    const float4 v0 = *(const float4*)(pf + ofs);
    const float4 v1 = *(const float4*)(pf + ofs + 4);
    uint4 r;
    r.x = cvt_pk_bf16(v0.x, v0.y); r.y = cvt_pk_bf16(v0.z, v0.w);
    r.z = cvt_pk_bf16(v1.x, v1.y); r.w = cvt_pk_bf16(v1.z, v1.w);
    return r;
  };
  f32x4 acc[4][4];
  #pragma unroll
  for (int i = 0; i < 4; ++i) {
    #pragma unroll
    for (int j = 0; j < 4; ++j) acc[i][j] = (f32x4){0.f, 0.f, 0.f, 0.f};
  }
  for (int k0 = 0; k0 < 512; k0 += 32) {
    const uint4 a0 = ld8(Ab, Af, ar0 + k0 + sch * 8, AF32);
    const uint4 a1 = ld8(Ab, Af, ar1 + k0 + sch * 8, AF32);
    const uint4 b0 = ld8(Wb, Wf, br0 + k0 + sch * 8, WF32);
    const uint4 b1 = ld8(Wb, Wf, br1 + k0 + sch * 8, WF32);
    __syncthreads();
    *(uint4*)(&As[srow][sch * 8])      = a0;
    *(uint4*)(&As[64 + srow][sch * 8]) = a1;
    *(uint4*)(&Bs[srow][sch * 8])      = b0;
    *(uint4*)(&Bs[64 + srow][sch * 8]) = b1;
    __syncthreads();
    s16x8 af[4], bfr[4];
    #pragma unroll
    for (int mi = 0; mi < 4; ++mi)
      af[mi] = *(const s16x8*)(&As[wr * 64 + mi * 16 + lrow][lk * 8]);
    #pragma unroll
    for (int ni = 0; ni < 4; ++ni)
      bfr[ni] = *(const s16x8*)(&Bs[wc * 64 + ni * 16 + lrow][lk * 8]);
    #pragma unroll
    for (int mi = 0; mi < 4; ++mi) {
      #pragma unroll
      for (int ni = 0; ni < 4; ++ni)
        acc[mi][ni] = __builtin_amdgcn_mfma_f32_16x16x32_bf16(
            af[mi], bfr[ni], acc[mi][ni], 0, 0, 0);
    }
  }
  #pragma unroll
  for (int mi = 0; mi < 4; ++mi) {
    #pragma unroll
    for (int r = 0; r < 4; ++r) {
      const int m = m0 + wr * 64 + mi * 16 + 4 * lk + r;
      if (m >= M) continue;
      #pragma unroll
      for (int ni = 0; ni < 4; ++ni) {
        const int n = n0 + wc * 64 + ni * 16 + lrow;
        const float v = acc[mi][ni][r] + bias[n];
        if (EPI == 0) {
          const int which = n >> 9, y = (n >> 6) & 7, c = n & 63;
          const int b_ = m / NQ, tok = m - b_ * NQ;
          ((ushort_t*)outp)[((((size_t)which * BB + b_) * NHH + y) * NQ + tok) * HDIM + c] = f2bf(v);
        } else {
          ((float*)outp)[(size_t)m * 512 + n] = v;
        }
      }
    }
  }
}

// ---------------------------------------------------------------------------
// Depthwise 3x3 pool + LayerNorm over HD=64.  MODE 0: plain bf16 row (v).
// MODE 1: q -> q_bf (unscaled) + qaug[0:64]=q*SCALE, [64:128]=0.
// MODE 2: k -> kaug[0:64]=k, [64:120]=one-hot(kh,kw), [120:128]=0.
// ---------------------------------------------------------------------------
template<int MODE>
__global__ __launch_bounds__(256) void pool_ln_kernel(
    const ushort_t* __restrict__ in, ushort_t* __restrict__ out0,
    ushort_t* __restrict__ out1,
    const float* __restrict__ cw, const float* __restrict__ lnw,
    const float* __restrict__ lnb, int stride, int OW, int R) {
  const int tid = threadIdx.x;
  const int c = tid & 63;
  const int rid = blockIdx.x * 4 + (tid >> 6);
  const int by = rid / R;
  const int n = rid - by * R;
  const ushort_t* ibase = in + (size_t)by * NQ * HDIM;
  float val;
  if (n == 0) {
    val = bf2f(ibase[c]);
  } else {
    const int p = n - 1;
    const int ho = p / OW, wo = p - ho * OW;
    float s = 0.f;
    #pragma unroll
    for (int dh = 0; dh < 3; ++dh) {
      const int hh = ho * stride + dh - 1;
      if (hh < 0 || hh >= 56) continue;
      #pragma unroll
      for (int dw = 0; dw < 3; ++dw) {
        const int ww = wo * stride + dw - 1;
        if (ww < 0 || ww >= 56) continue;
        s += cw[c * 9 + dh * 3 + dw] * bf2f(ibase[(size_t)(1 + hh * 56 + ww) * HDIM + c]);
      }
    }
    val = s;
  }
  float sum = val, sq = val * val;
  #pragma unroll
  for (int off = 32; off > 0; off >>= 1) {
    sum += __shfl_xor(sum, off);
    sq  += __shfl_xor(sq,  off);
  }
  const float mean = sum * (1.f / 64.f);
  const float var  = sq * (1.f / 64.f) - mean * mean;
  const float rs = rsqrtf(var + 1e-6f);
  const float lno = (val - mean) * rs * lnw[c] + lnb[c];
  if (MODE == 0) {
    out0[(size_t)rid * HDIM + c] = f2bf(lno);
  } else if (MODE == 1) {
    out0[(size_t)rid * HDIM + c] = f2bf(lno);
    out1[(size_t)rid * AUG + c] = f2bf(lno * SCALE);
    out1[(size_t)rid * AUG + 64 + c] = 0;
  } else {
    out0[(size_t)rid * AUG + c] = f2bf(lno);
    ushort_t aug = 0;
    if (n >= 1) {
      const int p = n - 1;
      const int kh = p / 28, kw = p - 28 * kh;
      if (c < 28) { if (c == kh) aug = 0x3F80; }
      else if (c < 56) { if (c - 28 == kw) aug = 0x3F80; }
    }
    out0[(size_t)rid * AUG + 64 + c] = aug;
  }
}

// ---------------------------------------------------------------------------
// V (row-major per head) -> V^T (64 channels x VTP cols), zero-padded cols.
// ---------------------------------------------------------------------------
__global__ __launch_bounds__(256) void transpose_v_kernel(
    const ushort_t* __restrict__ vin, ushort_t* __restrict__ vtout) {
  __shared__ ushort_t T[64][65];
  const int tid = threadIdx.x;
  const int by = blockIdx.y;
  const int n0 = blockIdx.x * 64;
  #pragma unroll
  for (int half = 0; half < 2; ++half) {
    const int idx = tid + half * 256;
    const int r = idx >> 3, s = idx & 7;
    const int n = n0 + r;
    uint4 d = make_uint4(0u, 0u, 0u, 0u);
    if (n < NKV) d = *(const uint4*)(vin + ((size_t)by * NKV + n) * HDIM + s * 8);
    const ushort_t* dp = (const ushort_t*)&d;
    #pragma unroll
    for (int e = 0; e < 8; ++e) T[r][s * 8 + e] = dp[e];
  }
  __syncthreads();
  #pragma unroll
  for (int half = 0; half < 2; ++half) {
    const int idx = tid + half * 256;
    const int c = idx >> 3, g = idx & 7;
    ushort_t pk[8];
    #pragma unroll
    for (int e = 0; e < 8; ++e) pk[e] = T[g * 8 + e][c];
    *(uint4*)(vtout + ((size_t)by * 64 + c) * VTP + n0 + g * 8) = *(const uint4*)pk;
  }
}

// ---------------------------------------------------------------------------
// MFMA rel-bias -> scatter bf16 directly into qaug channels 64+mode*28+kh.
// ---------------------------------------------------------------------------
__global__ __launch_bounds__(256) void relbias_mfma_kernel(
    const ushort_t* __restrict__ qb, const float* __restrict__ rph,
    const float* __restrict__ rpw, ushort_t* __restrict__ qaug) {
  const int tid = threadIdx.x;
  const int l = tid & 63, w = tid >> 6;
  const int lrow = l & 15, lk = l >> 4;
  const int hw = blockIdx.y;
  const int mode = blockIdx.z;
  const int r0 = blockIdx.x * 256 + w * 64;
  const float* tab = mode ? rpw : rph;
  s16x8 bfr[2][2];
  #pragma unroll
  for (int ni = 0; ni < 2; ++ni) {
    const int kh = ni * 16 + lrow;
    int trow = hw - 2 * kh + 54;
    if (trow < 0) trow = 0;
    const float* tr = tab + (size_t)trow * 64 + lk * 8;
    #pragma unroll
    for (int k0 = 0; k0 < 2; ++k0) {
      const float4 t0 = *(const float4*)(tr + k0 * 32);
      const float4 t1 = *(const float4*)(tr + k0 * 32 + 4);
      s16x8 bb;
      bb[0] = (short)f2bf(t0.x); bb[1] = (short)f2bf(t0.y);
      bb[2] = (short)f2bf(t0.z); bb[3] = (short)f2bf(t0.w);
      bb[4] = (short)f2bf(t1.x); bb[5] = (short)f2bf(t1.y);
      bb[6] = (short)f2bf(t1.z); bb[7] = (short)f2bf(t1.w);
      bfr[ni][k0] = bb;
    }
  }
  s16x8 af[4][2];
  #pragma unroll
  for (int mi = 0; mi < 4; ++mi) {
    const int rA = r0 + mi * 16 + lrow;
    const int by = rA / 56, oth = rA - 56 * by;
    const int tok = mode ? (1 + oth * 56 + hw) : (1 + hw * 56 + oth);
    const ushort_t* qp = qb + ((size_t)by * NQ + tok) * HDIM + lk * 8;
    af[mi][0] = *(const s16x8*)(qp);
    af[mi][1] = *(const s16x8*)(qp + 32);
  }
  f32x4 acc[4][2];
  #pragma unroll
  for (int mi = 0; mi < 4; ++mi) {
    #pragma unroll
    for (int ni = 0; ni < 2; ++ni) acc[mi][ni] = (f32x4){0.f, 0.f, 0.f, 0.f};
  }
  #pragma unroll
  for (int k0 = 0; k0 < 2; ++k0) {
    #pragma unroll
    for (int mi = 0; mi < 4; ++mi) {
      #pragma unroll
      for (int ni = 0; ni < 2; ++ni)
        acc[mi][ni] = __builtin_amdgcn_mfma_f32_16x16x32_bf16(
            af[mi][k0], bfr[ni][k0], acc[mi][ni], 0, 0, 0);
    }
  }
  const int augofs = 64 + mode * 28;
  #pragma unroll
  for (int mi = 0; mi < 4; ++mi) {
    #pragma unroll
    for (int r = 0; r < 4; ++r) {
      const int row = r0 + mi * 16 + 4 * lk + r;
      const int by = row / 56, oth = row - 56 * by;
      const int tok = 1 + (mode ? (oth * 56 + hw) : (hw * 56 + oth));
      ushort_t* orow = qaug + ((size_t)by * NQ + tok) * AUG + augofs;
      #pragma unroll
      for (int ni = 0; ni < 2; ++ni) {
        const int kh = ni * 16 + lrow;
        if (kh < 28) orow[kh] = f2bf(acc[mi][ni][r]);
      }
    }
  }
}

// ---------------------------------------------------------------------------
// Flash attention with bias folded into QK^T via augmented channels.
// 32x32 MFMA, swapped operands (S^T, O^T).  128 q/block, 13 iters x 64 k.
// ---------------------------------------------------------------------------
__global__ __launch_bounds__(256) void attn_mfma32_kernel(
    const ushort_t* __restrict__ qaug, const ushort_t* __restrict__ kaug,
    const ushort_t* __restrict__ qb, const ushort_t* __restrict__ vt,
    ushort_t* __restrict__ outp) {
  __shared__ ushort_t Kl[64 * AUG];    // 64 rows x 256B (16 slots)
  __shared__ ushort_t Vl[64 * 64];     // 64 ch rows x 128B (8 slots)
  const int tid = threadIdx.x;
  const int l = tid & 63, w = tid >> 6;
  const int h = l >> 5, q5 = l & 31;
  const int by = blockIdx.y;
  const int qt0 = blockIdx.x * 128;
  const int qloc = w * 32 + q5;
  const int qglob = qt0 + qloc;
  const int qcl = qglob < NQ ? qglob : NQ - 1;
  // Q fragments (loop-invariant): B-frag col = q5, k(c) = cb*16+8h+i, 8 cb
  const ushort_t* qrow = qaug + ((size_t)by * NQ + qcl) * AUG;
  s16x8 qf[8];
  #pragma unroll
  for (int cb = 0; cb < 8; ++cb)
    qf[cb] = *(const s16x8*)(qrow + cb * 16 + h * 8);
  f32x16 ot0, ot1;
  #pragma unroll
  for (int i = 0; i < 16; ++i) { ot0[i] = 0.f; ot1[i] = 0.f; }
  float mr = -1e30f, lr = 0.f;
  const int krow = tid >> 2, ks4 = (tid & 3) * 4;      // Kaug staging
  const int vrow = tid >> 3, vslot = tid & 7;          // V^T staging
  int jK = krow; if (jK > NKV - 1) jK = NKV - 1;
  #pragma unroll 1
  for (int it = 0; it < 13; ++it) {
    const int j0 = it * 64;
    jK = j0 + krow; if (jK > NKV - 1) jK = NKV - 1;
    const ushort_t* ksrc = kaug + ((size_t)by * NKV + jK) * AUG + ks4 * 8;
    const uint4 kd0 = *(const uint4*)(ksrc);
    const uint4 kd1 = *(const uint4*)(ksrc + 8);
    const uint4 kd2 = *(const uint4*)(ksrc + 16);
    const uint4 kd3 = *(const uint4*)(ksrc + 24);
    const uint4 vd0 = *(const uint4*)(vt + ((size_t)by * 64 + vrow) * VTP + j0 + vslot * 8);
    const uint4 vd1 = *(const uint4*)(vt + ((size_t)by * 64 + vrow + 32) * VTP + j0 + vslot * 8);
    __syncthreads();
    {
      char* kbase = (char*)Kl + krow * 256;
      const int rm = krow & 15;
      *(uint4*)(kbase + (((ks4 + 0) ^ rm) << 4)) = kd0;
      *(uint4*)(kbase + (((ks4 + 1) ^ rm) << 4)) = kd1;
      *(uint4*)(kbase + (((ks4 + 2) ^ rm) << 4)) = kd2;
      *(uint4*)(kbase + (((ks4 + 3) ^ rm) << 4)) = kd3;
      *(uint4*)((char*)Vl + vrow * 128 + (((vslot ^ (vrow & 7)) & 7) << 4)) = vd0;
      *(uint4*)((char*)Vl + (vrow + 32) * 128 + (((vslot ^ ((vrow + 32) & 7)) & 7) << 4)) = vd1;
    }
    __syncthreads();
    // S^T = Kaug @ Qaug^T : D col = q; bias already inside
    f32x16 st0, st1;
    #pragma unroll
    for (int i = 0; i < 16; ++i) { st0[i] = 0.f; st1[i] = 0.f; }
    #pragma unroll
    for (int cb = 0; cb < 8; ++cb) {
      st0 = __builtin_amdgcn_mfma_f32_32x32x16_bf16(
          lds_frag16(Kl, q5, cb * 2 + h), qf[cb], st0, 0, 0, 0);
      st1 = __builtin_amdgcn_mfma_f32_32x32x16_bf16(
          lds_frag16(Kl, 32 + q5, cb * 2 + h), qf[cb], st1, 0, 0, 0);
    }
    float pa[16], pb[16];
    #pragma unroll
    for (int r = 0; r < 16; ++r) { pa[r] = st0[r]; pb[r] = st1[r]; }
    if (it == 12) {   // tail mask: j0=768; invalid j >= 785
      #pragma unroll
      for (int r = 0; r < 16; ++r) {
        const int klocal = (r & 3) + 8 * (r >> 2) + 4 * h;
        if (768 + klocal >= NKV) pa[r] = -1e30f;
        pb[r] = -1e30f;
      }
    }
    // online softmax (lane owns q-row; partner lane l^32 holds other half)
    float mloc = pa[0];
    #pragma unroll
    for (int r = 1; r < 16; ++r) mloc = fmaxf(mloc, pa[r]);
    #pragma unroll
    for (int r = 0; r < 16; ++r) mloc = fmaxf(mloc, pb[r]);
    mloc = fmaxf(mloc, __shfl_xor(mloc, 32));
    const float mn = fmaxf(mr, mloc);
    const float sc = __expf(mr - mn);
    mr = mn;
    float ps = 0.f;
    #pragma unroll
    for (int r = 0; r < 16; ++r) { pa[r] = __expf(pa[r] - mn); ps += pa[r]; }
    #pragma unroll
    for (int r = 0; r < 16; ++r) { pb[r] = __expf(pb[r] - mn); ps += pb[r]; }
    ps += __shfl_xor(ps, 32);
    lr = lr * sc + ps;
    #pragma unroll
    for (int i = 0; i < 16; ++i) { ot0[i] *= sc; ot1[i] *= sc; }
    // pack P -> bf16 B-frags, accumulate O^T = V^T @ P^T
    auto pvstep = [&](const float (&pv)[16], int kt) {
      #pragma unroll
      for (int kbk = 0; kbk < 2; ++kbk) {
        const unsigned int pk01 = cvt_pk_bf16(pv[kbk * 8 + 0], pv[kbk * 8 + 1]);
        const unsigned int pk23 = cvt_pk_bf16(pv[kbk * 8 + 2], pv[kbk * 8 + 3]);
        const unsigned int pk45 = cvt_pk_bf16(pv[kbk * 8 + 4], pv[kbk * 8 + 5]);
        const unsigned int pk67 = cvt_pk_bf16(pv[kbk * 8 + 6], pv[kbk * 8 + 7]);
        const unsigned int sA = (unsigned int)__shfl_xor((int)pk01, 32);
        const unsigned int sB = (unsigned int)__shfl_xor((int)pk45, 32);
        const unsigned int sC = (unsigned int)__shfl_xor((int)pk23, 32);
        const unsigned int sD = (unsigned int)__shfl_xor((int)pk67, 32);
        int4 fw;
        fw.x = (int)(h ? sB : pk01);
        fw.y = (int)(h ? sD : pk23);
        fw.z = (int)(h ? pk45 : sA);
        fw.w = (int)(h ? pk67 : sC);
        s16x8 pf;
        __builtin_memcpy(&pf, &fw, 16);
        const int slot = kt * 4 + kbk * 2 + h;
        ot0 = __builtin_amdgcn_mfma_f32_32x32x16_bf16(
            lds_frag8(Vl, q5, slot), pf, ot0, 0, 0, 0);
        ot1 = __builtin_amdgcn_mfma_f32_32x32x16_bf16(
            lds_frag8(Vl, 32 + q5, slot), pf, ot1, 0, 0, 0);
      }
    };
    pvstep(pa, 0);
    pvstep(pb, 1);
  }
  // epilogue
  const float inv = 1.f / lr;
  if (qglob < NQ) {
    const int b_ = by >> 3, y_ = by & 7;
    ushort_t* obase = outp + ((size_t)b_ * NQ + qglob) * 512 + (size_t)y_ * 64;
    const ushort_t* rbase = qb + ((size_t)by * NQ + qglob) * HDIM;
    #pragma unroll
    for (int ch = 0; ch < 2; ++ch) {
      #pragma unroll
      for (int rg = 0; rg < 4; ++rg) {
        const int c0 = ch * 32 + 8 * rg + 4 * h;
        float vv[4];
        #pragma unroll
        for (int e = 0; e < 4; ++e)
          vv[e] = (ch ? ot1[rg * 4 + e] : ot0[rg * 4 + e]) * inv;
        if (qglob > 0) {
          #pragma unroll
          for (int e = 0; e < 4; ++e) vv[e] += bf2f(rbase[c0 + e]);
        }
        ushort_t pk[4] = { f2bf(vv[0]), f2bf(vv[1]), f2bf(vv[2]), f2bf(vv[3]) };
        *(uint2*)(obase + c0) = *(const uint2*)pk;
      }
    }
  }
}

// ---------------------------------------------------------------------------
extern "C" void kernel_launch(void* const* d_in, const int* in_sizes, int n_in,
                              void* d_out, int out_size, void* d_ws, size_t ws_size,
                              hipStream_t stream) {
  const float* x        = (const float*)d_in[0];
  const float* qkv_w    = (const float*)d_in[1];
  const float* qkv_b    = (const float*)d_in[2];
  const float* proj_w   = (const float*)d_in[3];
  const float* proj_b   = (const float*)d_in[4];
  const float* pool_q_w = (const float*)d_in[5];
  const float* pool_k_w = (const float*)d_in[6];
  const float* pool_v_w = (const float*)d_in[7];
  const float* lnq_w    = (const float*)d_in[8];
  const float* lnq_b    = (const float*)d_in[9];
  const float* lnk_w    = (const float*)d_in[10];
  const float* lnk_b    = (const float*)d_in[11];
  const float* lnv_w    = (const float*)d_in[12];
  const float* lnv_b    = (const float*)d_in[13];
  const float* rel_pos_h = (const float*)d_in[14];
  const float* rel_pos_w = (const float*)d_in[15];

  constexpr size_t E1 = (size_t)BB * NHH * NQ * HDIM;   // 12,849,152
  char* ws = (char*)d_ws;
  size_t off = 0;
  ushort_t* qkv_raw = (ushort_t*)(ws + off); off += 3 * E1 * 2;
  ushort_t* q_bf    = (ushort_t*)(ws + off); off += E1 * 2;
  ushort_t* qaug    = (ushort_t*)(ws + off); off += (size_t)BB * NHH * NQ * AUG * 2;
  ushort_t* kaug    = (ushort_t*)(ws + off); off += (size_t)BB * NHH * NKV * AUG * 2;
  ushort_t* v_bf    = (ushort_t*)(ws + off); off += (size_t)BB * NHH * NKV * HDIM * 2;
  ushort_t* v_t     = (ushort_t*)(ws + off); off += (size_t)64 * 64 * VTP * 2;
  ushort_t* attn_bf = qkv_raw;   // reuse (raw consumed by pools before attn)

  // 1) QKV GEMM (f32 inputs cast in staging) -> qkv_raw scatter
  mfma_gemm_bt<0, true, true><<<dim3(12, 197), 256, 0, stream>>>(
      x, qkv_w, qkv_b, (void*)qkv_raw, MROWS);

  // 2) pool + LN
  pool_ln_kernel<1><<<(64 * NQ) / 4,  256, 0, stream>>>(qkv_raw,          q_bf, qaug, pool_q_w, lnq_w, lnq_b, 1, 56, NQ);
  pool_ln_kernel<2><<<(64 * NKV) / 4, 256, 0, stream>>>(qkv_raw + E1,     kaug, nullptr, pool_k_w, lnk_w, lnk_b, 2, 28, NKV);
  pool_ln_kernel<0><<<(64 * NKV) / 4, 256, 0, stream>>>(qkv_raw + 2 * E1, v_bf, nullptr, pool_v_w, lnv_w, lnv_b, 2, 28, NKV);

  // 2b) V -> V^T
  transpose_v_kernel<<<dim3(13, 64), 256, 0, stream>>>(v_bf, v_t);

  // 3) rel bias via MFMA -> scatter bf16 into qaug[64:120]
  relbias_mfma_kernel<<<dim3(14, 56, 2), 256, 0, stream>>>(q_bf, rel_pos_h, rel_pos_w, qaug);

  // 4) flash attention (bias folded into QK^T) -> bf16 (B,N,512)
  attn_mfma32_kernel<<<dim3(25, 64), 256, 0, stream>>>(qaug, kaug, q_bf, v_t, attn_bf);

  // 5) proj GEMM -> d_out f32
  mfma_gemm_bt<1, false, true><<<dim3(4, 197), 256, 0, stream>>>(
      attn_bf, proj_w, proj_b, d_out, MROWS);
}